// Round 7
// baseline (241.076 us; speedup 1.0000x reference)
//
#include <hip/hip_runtime.h>
#include <hip/hip_cooperative_groups.h>
#include <math.h>

namespace cg = cooperative_groups;

#define NNODE 2048
#define NEDGE 32768
#define DD 64
#define GG 16
#define NPG 128   // nodes per graph
#define PP 500    // kde grid points
#define QQ 20     // quantiles
#define CAP 64    // adjacency bucket capacity (max in-degree ~35 here)
#define NBLK 256  // 1 block/CU -> cooperative co-residency guaranteed
#define NCOMP (NBLK - 1)   // blocks doing mega units; last block does CSR fill

__device__ __forceinline__ float fexp2(float x) { return __builtin_amdgcn_exp2f(x); }
__device__ __forceinline__ float frcp(float x)  { return __builtin_amdgcn_rcpf(x); }
__device__ __forceinline__ float frsq(float x)  { return __builtin_amdgcn_rsqf(x); }

struct __align__(8) f2 { float x, y; };

struct KdeS { f2 bc[NPG]; f2 cg[512]; float sred[8]; float wtot[8]; float kfv[QQ]; };
struct AttS { float sc[NPG]; float part[8][DD]; float pooled[DD]; };
struct XwS  { float Ws[DD][DD]; float xr[8][DD]; };
union SmemU { KdeS k; AttS a; XwS x; };

struct Params {
    const float *x; const int *ei;
    const float *gcn_W0, *gcn_b0, *gcn_W1, *gcn_b1;
    const float *lp_W0, *lp_b0, *lp_W1, *lp_b1;
    const float *cls_W, *cls_b;
    const float *kp_W0, *kp_b0, *kp_W1, *kp_b1;
    const float *gate_W0, *gate_b0, *gate_W1, *gate_b1, *gate_W2, *gate_b2;
    const float *beta, *h0s;
    int *cnt, *csr;
    float *A, *B, *hb, *kpart, *out;
};

// ---------- attention-pool helper (512 threads) ----------
__device__ __forceinline__ void att_pool(AttS& s, const float* __restrict__ xg,
                                         const float* __restrict__ gW, float gb) {
    int t = threadIdx.x, lane = t & 63, wid = t >> 6;
    int node = t >> 2, seg = t & 3;
    const float* row = xg + node * DD + seg * 16;
    const float* gw = gW + seg * 16;
    float v = 0.f;
    #pragma unroll
    for (int k = 0; k < 16; k++) v = fmaf(row[k], gw[k], v);
    v += __shfl_xor(v, 1);
    v += __shfl_xor(v, 2);
    if (seg == 0) s.sc[node] = v + gb;
    __syncthreads();
    if (wid == 0) {
        float v0 = s.sc[lane], v1 = s.sc[lane + 64];
        float m = fmaxf(v0, v1);
        for (int o = 32; o; o >>= 1) m = fmaxf(m, __shfl_xor(m, o));
        float e0 = __expf(v0 - m), e1 = __expf(v1 - m);
        float ssum = e0 + e1;
        for (int o = 32; o; o >>= 1) ssum += __shfl_xor(ssum, o);
        float inv = frcp(ssum);
        s.sc[lane] = e0 * inv;
        s.sc[lane + 64] = e1 * inv;
    }
    __syncthreads();
    int d2 = t & 63, ch = t >> 6;
    const float* base = xg + ch * 16 * DD + d2;
    const float* av = s.sc + ch * 16;
    float p = 0.f;
    #pragma unroll
    for (int i = 0; i < 16; i++) p = fmaf(av[i], base[i * DD], p);
    s.part[ch][d2] = p;
    __syncthreads();
    if (t < DD) {
        float pd = 0.f;
        #pragma unroll
        for (int c2 = 0; c2 < 8; c2++) pd += s.part[c2][t];
        s.pooled[t] = pd;
    }
    __syncthreads();
}

// ---------- one mega unit: vb<1024 KDE | vb<1040 att-pool | else xw (unscaled) ----------
__device__ void mega_unit(SmemU& sm, int vb,
    const float* __restrict__ xin,
    float* __restrict__ xwout, float* __restrict__ hbL, float* __restrict__ kpartL,
    const float* __restrict__ gcnW,
    const float* __restrict__ gateW, const float* __restrict__ gateB,
    const float* __restrict__ lpW, const float* __restrict__ lpB,
    const float* __restrict__ kpW) {
    int t = threadIdx.x, lane = t & 63, wid = t >> 6;
    __syncthreads();   // protect LDS reuse across consecutive units

    if (vb < GG * DD) {
        int g = vb >> 6, d = vb & 63;
        const float* xg = xin + g * NPG * DD + d;
        float a = 0.f;
        if (t < NPG) a = xg[t * DD];
        if (wid < 2) {
            float mn = a, mx = a, smv = a;
            for (int o = 32; o; o >>= 1) {
                mn = fminf(mn, __shfl_xor(mn, o));
                mx = fmaxf(mx, __shfl_xor(mx, o));
                smv += __shfl_xor(smv, o);
            }
            if (lane == 0) {
                sm.k.sred[wid * 3 + 0] = mn;
                sm.k.sred[wid * 3 + 1] = mx;
                sm.k.sred[wid * 3 + 2] = smv;
            }
        }
        __syncthreads();
        float mn = fminf(sm.k.sred[0], sm.k.sred[3]) - 1e-6f;
        float mx = fmaxf(sm.k.sred[1], sm.k.sred[4]) + 1e-6f;
        float mean = (sm.k.sred[2] + sm.k.sred[5]) * (1.f / 128.f);
        if (wid < 2) {
            float dv = a - mean;
            float sq = dv * dv;
            for (int o = 32; o; o >>= 1) sq += __shfl_xor(sq, o);
            if (lane == 0) sm.k.sred[6 + wid] = sq;
        }
        __syncthreads();
        float var = fmaxf((sm.k.sred[6] + sm.k.sred[7]) * (1.f / 128.f), 0.f);
        float sd = sqrtf(var) + (1e-8f / 3.0f);
        float h = 0.4016648901252554f * sd;          // 1.06 * 128^-0.2 * std
        float A = -0.5f * 1.4426950408889634f * frcp(h * h);
        if (t < NPG) { f2 v; v.x = -2.f * A * a; v.y = A * a * a; sm.k.bc[t] = v; }
        __syncthreads();
        float step = (mx - mn) * (1.f / 499.f);
        float gp = fmaf(step, (float)t, mn);
        float gA = A * gp * gp;
        const float4* bc4 = (const float4*)sm.k.bc;
        float ac0 = 0.f, ac1 = 0.f, ac2 = 0.f, ac3 = 0.f;
        #pragma unroll 4
        for (int j4 = 0; j4 < 64; j4 += 2) {
            float4 p = bc4[j4], q = bc4[j4 + 1];
            ac0 += fexp2(gA + fmaf(p.x, gp, p.y));
            ac1 += fexp2(gA + fmaf(p.z, gp, p.w));
            ac2 += fexp2(gA + fmaf(q.x, gp, q.y));
            ac3 += fexp2(gA + fmaf(q.z, gp, q.w));
        }
        float invnh = frcp(128.f * h * 2.5066282746310002f);
        float dens = (t < PP) ? ((ac0 + ac1) + (ac2 + ac3)) * invnh : 0.f;
        float sc2 = dens;
        for (int o = 1; o < 64; o <<= 1) {
            float u = __shfl_up(sc2, o);
            if (lane >= o) sc2 += u;
        }
        if (lane == 63) sm.k.wtot[wid] = sc2;
        __syncthreads();
        float offs = 0.f, total = 0.f;
        #pragma unroll
        for (int w = 0; w < 8; w++) {
            float wv = sm.k.wtot[w];
            if (w < wid) offs += wv;
            total += wv;
        }
        float c = (offs + sc2) * frcp(fmaxf(total, 1e-8f));
        f2 cgv; cgv.x = (t < PP) ? c : 4.0f; cgv.y = (t < PP) ? gp : 0.f;
        sm.k.cg[t] = cgv;
        __syncthreads();
        int grp = t >> 4, sub = t & 15;
        if (grp < QQ) {
            float qv = (float)grp * (1.f / 19.f);
            float sw0 = 0.f, sw1 = 0.f, sg0 = 0.f, sg1 = 0.f;
            #pragma unroll
            for (int i = 0; i < 32; i += 2) {
                f2 v0 = sm.k.cg[i * 16 + sub];
                f2 v1 = sm.k.cg[(i + 1) * 16 + sub];
                float e0 = fexp2(fabsf(v0.x - qv) * 144.26950408889634f);
                float e1 = fexp2(fabsf(v1.x - qv) * 144.26950408889634f);
                float w0 = frcp(1.f + e0), w1 = frcp(1.f + e1);
                sw0 += w0; sg0 = fmaf(w0, v0.y, sg0);
                sw1 += w1; sg1 = fmaf(w1, v1.y, sg1);
            }
            float sw = sw0 + sw1, sg = sg0 + sg1;
            #pragma unroll
            for (int o = 1; o < 16; o <<= 1) {
                sw += __shfl_xor(sw, o);
                sg += __shfl_xor(sg, o);
            }
            if (sub == 0) sm.k.kfv[grp] = sg * frcp(sw + 1e-8f);
        }
        __syncthreads();
        if (t < 16) {
            float v = 0.f;
            #pragma unroll
            for (int q = 0; q < QQ; q++) v = fmaf(sm.k.kfv[q], kpW[(d * QQ + q) * 16 + t], v);
            kpartL[vb * 16 + t] = v;
        }
    } else if (vb < GG * DD + GG) {
        int g = vb - GG * DD;
        att_pool(sm.a, xin + g * NPG * DD, gateW, gateB[0]);
        if (t < 16) {
            float o = lpB[t];
            #pragma unroll
            for (int d2 = 0; d2 < DD; d2++) o = fmaf(sm.a.pooled[d2], lpW[d2 * 16 + t], o);
            hbL[g * 16 + t] = o;
        }
    } else {
        // xw = x @ W (UNSCALED; dinv applied in gather), 8 rows per block-unit
        int rb = vb - (GG * DD + GG);
        int r0 = rb * 8;
        float4* Wv = (float4*)&sm.x.Ws[0][0];
        const float4* Gv = (const float4*)gcnW;
        Wv[t] = Gv[t];
        Wv[t + 512] = Gv[t + 512];
        sm.x.xr[wid][lane] = xin[(r0 + wid) * DD + lane];
        __syncthreads();
        float s = 0.f;
        #pragma unroll
        for (int k = 0; k < DD; k++) s = fmaf(sm.x.xr[wid][k], sm.x.Ws[k][lane], s);
        xwout[(r0 + wid) * DD + lane] = s;
    }
}

// ---------- gather: cur[n] = dinv[n]*(sum_s dinv[s]*xw[s] + dinv[n]*xw[n]) + b ----------
__device__ void gather_unit(const int* __restrict__ cnt, const int* __restrict__ csr,
                            const float* __restrict__ xw, const float* __restrict__ bvec,
                            float* __restrict__ cur) {
    int t = threadIdx.x, lane = t & 63, wid = t >> 6;
    int n = blockIdx.x * 8 + wid;
    int ecn = cnt[n];
    int ec = ecn > CAP ? CAP : ecn;
    const int* lst = csr + n * CAP;
    float sum0 = 0.f, sum1 = 0.f;
    int j = 0;
    for (; j + 2 <= ec; j += 2) {
        int s0 = lst[j], s1 = lst[j + 1];
        float d0 = frsq((float)cnt[s0] + 1.f);
        float d1 = frsq((float)cnt[s1] + 1.f);
        sum0 = fmaf(d0, xw[s0 * DD + lane], sum0);
        sum1 = fmaf(d1, xw[s1 * DD + lane], sum1);
    }
    if (j < ec) {
        int s0 = lst[j];
        sum0 = fmaf(frsq((float)cnt[s0] + 1.f), xw[s0 * DD + lane], sum0);
    }
    float di = frsq((float)ecn + 1.f);
    cur[n * DD + lane] = di * ((sum0 + sum1) + di * xw[n * DD + lane]) + bvec[lane];
}

// ---------- the single cooperative kernel ----------
__global__ __launch_bounds__(512) void k_all(Params p) {
    __shared__ SmemU sm;
    __shared__ float red[16];
    cg::grid_group grid = cg::this_grid();
    int b = blockIdx.x, t = threadIdx.x;

    // ===== P0: CSR zero+fill (block NBLK-1, serial) || mega L0 (blocks 0..NCOMP-1) =====
    if (b == NCOMP) {
        for (int i = t; i < NNODE; i += 512) p.cnt[i] = 0;
        __syncthreads();
        for (int e = t; e < NEDGE; e += 512) {
            int s = p.ei[e], dstn = p.ei[NEDGE + e];
            int pos = atomicAdd(&p.cnt[dstn], 1);
            if (pos < CAP) p.csr[dstn * CAP + pos] = s;
        }
    } else {
        #pragma unroll
        for (int k = 0; k < 6; k++) {
            int vb = b + NCOMP * k;
            if (vb < GG * DD + GG + NNODE / 8)
                mega_unit(sm, vb, p.x, p.A, p.hb, p.kpart,
                          p.gcn_W0, p.gate_W0, p.gate_b0, p.lp_W0, p.lp_b0, p.kp_W0);
        }
    }
    grid.sync();

    // ===== P1: gather L0 (all 256 blocks, 8 nodes each) =====
    gather_unit(p.cnt, p.csr, p.A, p.gcn_b0, p.B);
    grid.sync();

    // ===== P2: mega L1 =====
    if (b < NCOMP) {
        #pragma unroll
        for (int k = 0; k < 6; k++) {
            int vb = b + NCOMP * k;
            if (vb < GG * DD + GG + NNODE / 8)
                mega_unit(sm, vb, p.B, p.A, p.hb + 256, p.kpart + GG * DD * 16,
                          p.gcn_W1, p.gate_W1, p.gate_b1, p.lp_W1, p.lp_b1, p.kp_W1);
        }
    }
    grid.sync();

    // ===== P3: gather L1 =====
    gather_unit(p.cnt, p.csr, p.A, p.gcn_b1, p.B);
    grid.sync();

    // ===== P4: fin (blocks 0..15) =====
    if (b < GG) {
        int g = b;
        att_pool(sm.a, p.B + g * NPG * DD, p.gate_W2, p.gate_b2[0]);
        if (t < 16) {
            float h2 = p.cls_b[t];
            #pragma unroll
            for (int d2 = 0; d2 < DD; d2++) h2 = fmaf(sm.a.pooled[d2], p.cls_W[d2 * 16 + t], h2);
            const float* kp0 = p.kpart + g * DD * 16 + t;
            const float* kp1 = kp0 + GG * DD * 16;
            float s0 = 0.f, s1 = 0.f;
            #pragma unroll
            for (int d2 = 0; d2 < DD; d2++) {
                s0 += kp0[d2 * 16];
                s1 += kp1[d2 * 16];
            }
            float mo = (p.hb[g * 16 + t] + p.hb[256 + g * 16 + t] + h2) * (1.f / 3.f);
            float ko = (s0 + p.kp_b0[t] + s1 + p.kp_b1[t]) * 0.5f;
            red[t] = (mo + ko) * p.beta[t];
        }
        __syncthreads();
        if (t == 0) {
            float s = 0.f;
            #pragma unroll
            for (int j = 0; j < 16; j++) s += red[j];
            p.out[g] = s + p.h0s[0];
        }
    }
}

extern "C" void kernel_launch(void* const* d_in, const int* in_sizes, int n_in,
                              void* d_out, int out_size, void* d_ws, size_t ws_size,
                              hipStream_t stream) {
    Params hp;
    hp.x       = (const float*)d_in[0];
    hp.ei      = (const int*)  d_in[1];
    hp.gcn_W0  = (const float*)d_in[2];
    hp.gcn_b0  = (const float*)d_in[3];
    hp.gcn_W1  = (const float*)d_in[4];
    hp.gcn_b1  = (const float*)d_in[5];
    hp.lp_W0   = (const float*)d_in[6];
    hp.lp_b0   = (const float*)d_in[7];
    hp.lp_W1   = (const float*)d_in[8];
    hp.lp_b1   = (const float*)d_in[9];
    hp.cls_W   = (const float*)d_in[10];
    hp.cls_b   = (const float*)d_in[11];
    hp.kp_W0   = (const float*)d_in[12];
    hp.kp_b0   = (const float*)d_in[13];
    hp.kp_W1   = (const float*)d_in[14];
    hp.kp_b1   = (const float*)d_in[15];
    hp.gate_W0 = (const float*)d_in[16];
    hp.gate_b0 = (const float*)d_in[17];
    hp.gate_W1 = (const float*)d_in[18];
    hp.gate_b1 = (const float*)d_in[19];
    hp.gate_W2 = (const float*)d_in[20];
    hp.gate_b2 = (const float*)d_in[21];
    hp.beta    = (const float*)d_in[22];
    hp.h0s     = (const float*)d_in[23];

    float* ws = (float*)d_ws;
    hp.cnt   = (int*)ws;                        // [2048]
    hp.csr   = hp.cnt + NNODE;                  // [2048*64]
    hp.A     = (float*)(hp.csr + NNODE * CAP);  // xw [131072]
    hp.B     = hp.A + NNODE * DD;               // cur [131072]
    hp.hb    = hp.B + NNODE * DD;               // [512]
    hp.kpart = hp.hb + 512;                     // [2*1024*16]
    hp.out   = (float*)d_out;

    void* args[] = { &hp };
    hipLaunchCooperativeKernel((void*)k_all, dim3(NBLK), dim3(512), args, 0, stream);
}

// Round 8
// 151.424 us; speedup vs baseline: 1.5921x; 1.5921x over previous
//
#include <hip/hip_runtime.h>
#include <math.h>

#define NNODE 2048
#define NEDGE 32768
#define DD 64
#define GG 16
#define NPG 128   // nodes per graph
#define PP 500    // kde grid points
#define QQ 20     // quantiles
#define CAP 64    // adjacency bucket capacity (max in-degree ~35 here)

__device__ __forceinline__ float fexp2(float x) { return __builtin_amdgcn_exp2f(x); }
__device__ __forceinline__ float frcp(float x)  { return __builtin_amdgcn_rcpf(x); }
__device__ __forceinline__ float frsq(float x)  { return __builtin_amdgcn_rsqf(x); }

struct __align__(8) f2 { float x, y; };

struct KdeS { f2 bc[NPG]; f2 cg[512]; float sred[8]; float wtot[8]; float kfv[QQ]; };
struct AttS { float sc[NPG]; float part[8][DD]; float pooled[DD]; };
struct XwS  { float Ws[DD][DD]; float xr[8][DD]; };
struct CsrS { int cnti[NNODE]; };
union SmemU { KdeS k; AttS a; XwS x; CsrS c; };

// ---------- mega kernel: one unit per block ----------
// vb<1024: KDE | vb<1040: att-pool+lin head | vb<1296: xw=x@W (unscaled) | vb==1296: CSR build
__global__ __launch_bounds__(512) void k_mega(
    const float* __restrict__ xin, const int* __restrict__ ei,
    int* __restrict__ cnt, int* __restrict__ csr,
    float* __restrict__ xwout, float* __restrict__ hbL, float* __restrict__ kpartL,
    const float* __restrict__ gcnW,
    const float* __restrict__ gateW, const float* __restrict__ gateB,
    const float* __restrict__ lpW, const float* __restrict__ lpB,
    const float* __restrict__ kpW) {
    __shared__ SmemU sm;
    int vb = blockIdx.x, t = threadIdx.x, lane = t & 63, wid = t >> 6;

    if (vb < GG * DD) {
        // ================= KDE: one block per (g,d) =================
        int g = vb >> 6, d = vb & 63;
        const float* xg = xin + g * NPG * DD + d;
        float a = 0.f;
        if (t < NPG) a = xg[t * DD];
        if (wid < 2) {
            float mn = a, mx = a, smv = a;
            for (int o = 32; o; o >>= 1) {
                mn = fminf(mn, __shfl_xor(mn, o));
                mx = fmaxf(mx, __shfl_xor(mx, o));
                smv += __shfl_xor(smv, o);
            }
            if (lane == 0) {
                sm.k.sred[wid * 3 + 0] = mn;
                sm.k.sred[wid * 3 + 1] = mx;
                sm.k.sred[wid * 3 + 2] = smv;
            }
        }
        __syncthreads();
        float mn = fminf(sm.k.sred[0], sm.k.sred[3]) - 1e-6f;
        float mx = fmaxf(sm.k.sred[1], sm.k.sred[4]) + 1e-6f;
        float mean = (sm.k.sred[2] + sm.k.sred[5]) * (1.f / 128.f);
        if (wid < 2) {
            float dv = a - mean;
            float sq = dv * dv;
            for (int o = 32; o; o >>= 1) sq += __shfl_xor(sq, o);
            if (lane == 0) sm.k.sred[6 + wid] = sq;
        }
        __syncthreads();
        float var = fmaxf((sm.k.sred[6] + sm.k.sred[7]) * (1.f / 128.f), 0.f);
        float sd = sqrtf(var) + (1e-8f / 3.0f);
        float h = 0.4016648901252554f * sd;          // 1.06 * 128^-0.2 * std
        float A = -0.5f * 1.4426950408889634f * frcp(h * h);
        if (t < NPG) { f2 v; v.x = -2.f * A * a; v.y = A * a * a; sm.k.bc[t] = v; }
        __syncthreads();
        float step = (mx - mn) * (1.f / 499.f);
        float gp = fmaf(step, (float)t, mn);
        float gA = A * gp * gp;
        const float4* bc4 = (const float4*)sm.k.bc;
        float ac0 = 0.f, ac1 = 0.f, ac2 = 0.f, ac3 = 0.f;
        #pragma unroll 4
        for (int j4 = 0; j4 < 64; j4 += 2) {
            float4 p = bc4[j4], q = bc4[j4 + 1];
            ac0 += fexp2(gA + fmaf(p.x, gp, p.y));
            ac1 += fexp2(gA + fmaf(p.z, gp, p.w));
            ac2 += fexp2(gA + fmaf(q.x, gp, q.y));
            ac3 += fexp2(gA + fmaf(q.z, gp, q.w));
        }
        float invnh = frcp(128.f * h * 2.5066282746310002f);
        float dens = (t < PP) ? ((ac0 + ac1) + (ac2 + ac3)) * invnh : 0.f;
        float sc2 = dens;
        for (int o = 1; o < 64; o <<= 1) {
            float u = __shfl_up(sc2, o);
            if (lane >= o) sc2 += u;
        }
        if (lane == 63) sm.k.wtot[wid] = sc2;
        __syncthreads();
        float offs = 0.f, total = 0.f;
        #pragma unroll
        for (int w = 0; w < 8; w++) {
            float wv = sm.k.wtot[w];
            if (w < wid) offs += wv;
            total += wv;
        }
        float c = (offs + sc2) * frcp(fmaxf(total, 1e-8f));
        f2 cgv; cgv.x = (t < PP) ? c : 4.0f; cgv.y = (t < PP) ? gp : 0.f;
        sm.k.cg[t] = cgv;
        __syncthreads();
        int grp = t >> 4, sub = t & 15;
        if (grp < QQ) {
            float qv = (float)grp * (1.f / 19.f);
            float sw0 = 0.f, sw1 = 0.f, sg0 = 0.f, sg1 = 0.f;
            #pragma unroll
            for (int i = 0; i < 32; i += 2) {
                f2 v0 = sm.k.cg[i * 16 + sub];
                f2 v1 = sm.k.cg[(i + 1) * 16 + sub];
                float e0 = fexp2(fabsf(v0.x - qv) * 144.26950408889634f);
                float e1 = fexp2(fabsf(v1.x - qv) * 144.26950408889634f);
                float w0 = frcp(1.f + e0), w1 = frcp(1.f + e1);
                sw0 += w0; sg0 = fmaf(w0, v0.y, sg0);
                sw1 += w1; sg1 = fmaf(w1, v1.y, sg1);
            }
            float sw = sw0 + sw1, sg = sg0 + sg1;
            #pragma unroll
            for (int o = 1; o < 16; o <<= 1) {
                sw += __shfl_xor(sw, o);
                sg += __shfl_xor(sg, o);
            }
            if (sub == 0) sm.k.kfv[grp] = sg * frcp(sw + 1e-8f);
        }
        __syncthreads();
        if (t < 16) {
            float v = 0.f;
            #pragma unroll
            for (int q = 0; q < QQ; q++) v = fmaf(sm.k.kfv[q], kpW[(d * QQ + q) * 16 + t], v);
            kpartL[vb * 16 + t] = v;
        }
    } else if (vb < GG * DD + GG) {
        // ================= attention-pool + linear head =================
        int g = vb - GG * DD;
        const float* xg = xin + g * NPG * DD;
        int node = t >> 2, seg = t & 3;
        const float* row = xg + node * DD + seg * 16;
        const float* gw = gateW + seg * 16;
        float v = 0.f;
        #pragma unroll
        for (int k = 0; k < 16; k++) v = fmaf(row[k], gw[k], v);
        v += __shfl_xor(v, 1);
        v += __shfl_xor(v, 2);
        if (seg == 0) sm.a.sc[node] = v + gateB[0];
        __syncthreads();
        if (wid == 0) {
            float v0 = sm.a.sc[lane], v1 = sm.a.sc[lane + 64];
            float m = fmaxf(v0, v1);
            for (int o = 32; o; o >>= 1) m = fmaxf(m, __shfl_xor(m, o));
            float e0 = __expf(v0 - m), e1 = __expf(v1 - m);
            float ssum = e0 + e1;
            for (int o = 32; o; o >>= 1) ssum += __shfl_xor(ssum, o);
            float inv = frcp(ssum);
            sm.a.sc[lane] = e0 * inv;
            sm.a.sc[lane + 64] = e1 * inv;
        }
        __syncthreads();
        int d2 = t & 63, ch = t >> 6;
        const float* base = xg + ch * 16 * DD + d2;
        const float* av = sm.a.sc + ch * 16;
        float p = 0.f;
        #pragma unroll
        for (int i = 0; i < 16; i++) p = fmaf(av[i], base[i * DD], p);
        sm.a.part[ch][d2] = p;
        __syncthreads();
        if (t < DD) {
            float pd = 0.f;
            #pragma unroll
            for (int c2 = 0; c2 < 8; c2++) pd += sm.a.part[c2][t];
            sm.a.pooled[t] = pd;
        }
        __syncthreads();
        if (t < 16) {
            float o = lpB[t];
            #pragma unroll
            for (int d2_ = 0; d2_ < DD; d2_++) o = fmaf(sm.a.pooled[d2_], lpW[d2_ * 16 + t], o);
            hbL[g * 16 + t] = o;
        }
    } else if (vb < GG * DD + GG + NNODE / 8) {
        // ================= xw = x @ W (unscaled): 8 rows per block =================
        int rb = vb - (GG * DD + GG);
        int r0 = rb * 8;
        float4* Wv = (float4*)&sm.x.Ws[0][0];
        const float4* Gv = (const float4*)gcnW;
        Wv[t] = Gv[t];
        Wv[t + 512] = Gv[t + 512];
        sm.x.xr[wid][lane] = xin[(r0 + wid) * DD + lane];
        __syncthreads();
        float s = 0.f;
        #pragma unroll
        for (int k = 0; k < DD; k++) s = fmaf(sm.x.xr[wid][k], sm.x.Ws[k][lane], s);
        xwout[(r0 + wid) * DD + lane] = s;
    } else {
        // ================= CSR build (one self-contained block) =================
        int* cl = sm.c.cnti;
        for (int i = t; i < NNODE; i += 512) cl[i] = 0;
        __syncthreads();
        for (int e = t; e < NEDGE; e += 512) {
            int s = ei[e], dstn = ei[NEDGE + e];
            int pos = atomicAdd(&cl[dstn], 1);
            if (pos < CAP) csr[dstn * CAP + pos] = s;
        }
        __syncthreads();
        for (int i = t; i < NNODE; i += 512) cnt[i] = cl[i];
    }
}

// ---------- gather L0: cur[n] = dinv[n]*(sum_s dinv[s]*xw[s] + dinv[n]*xw[n]) + b ----------
__global__ __launch_bounds__(512) void k_gather(const int* __restrict__ cnt,
                                                const int* __restrict__ csr,
                                                const float* __restrict__ xw,
                                                const float* __restrict__ bvec,
                                                float* __restrict__ cur) {
    int t = threadIdx.x, lane = t & 63, wid = t >> 6;
    int n = blockIdx.x * 8 + wid;
    int ecn = cnt[n];
    int ec = ecn > CAP ? CAP : ecn;
    const int* lst = csr + n * CAP;
    float sum0 = 0.f, sum1 = 0.f;
    int j = 0;
    for (; j + 2 <= ec; j += 2) {
        int s0 = lst[j], s1 = lst[j + 1];
        sum0 = fmaf(frsq((float)cnt[s0] + 1.f), xw[s0 * DD + lane], sum0);
        sum1 = fmaf(frsq((float)cnt[s1] + 1.f), xw[s1 * DD + lane], sum1);
    }
    if (j < ec) {
        int s0 = lst[j];
        sum0 = fmaf(frsq((float)cnt[s0] + 1.f), xw[s0 * DD + lane], sum0);
    }
    float di = frsq((float)ecn + 1.f);
    cur[n * DD + lane] = di * ((sum0 + sum1) + di * xw[n * DD + lane]) + bvec[lane];
}

// ---------- gfin: per-graph gather-L1 into LDS + att-pool + heads + combine ----------
__global__ __launch_bounds__(512) void k_gfin(
    const int* __restrict__ cnt, const int* __restrict__ csr,
    const float* __restrict__ xw, const float* __restrict__ gcn_b1,
    const float* __restrict__ gW2, const float* __restrict__ gb2,
    const float* __restrict__ clsW, const float* __restrict__ clsB,
    const float* __restrict__ hb, const float* __restrict__ kpart,
    const float* __restrict__ kpb0, const float* __restrict__ kpb1,
    const float* __restrict__ beta, const float* __restrict__ h0s,
    float* __restrict__ out) {
    __shared__ float xs[NPG][DD];
    __shared__ AttS sa;
    __shared__ float red2[32][16];
    __shared__ float red[16];
    int g = blockIdx.x, t = threadIdx.x, lane = t & 63, wid = t >> 6;

    // gather this graph's 128 cur2 rows into LDS (wave wid: nodes wid*16..+15)
    for (int i = 0; i < 16; i++) {
        int nl = wid * 16 + i;
        int n = g * NPG + nl;
        int ecn = cnt[n];
        int ec = ecn > CAP ? CAP : ecn;
        const int* lst = csr + n * CAP;
        float s0 = 0.f, s1 = 0.f;
        int j = 0;
        for (; j + 2 <= ec; j += 2) {
            int a0 = lst[j], a1 = lst[j + 1];
            s0 = fmaf(frsq((float)cnt[a0] + 1.f), xw[a0 * DD + lane], s0);
            s1 = fmaf(frsq((float)cnt[a1] + 1.f), xw[a1 * DD + lane], s1);
        }
        if (j < ec) {
            int a0 = lst[j];
            s0 = fmaf(frsq((float)cnt[a0] + 1.f), xw[a0 * DD + lane], s0);
        }
        float di = frsq((float)ecn + 1.f);
        xs[nl][lane] = di * ((s0 + s1) + di * xw[n * DD + lane]) + gcn_b1[lane];
    }
    __syncthreads();

    // attention pool from LDS (gate_W2)
    int node = t >> 2, seg = t & 3;
    const float* gw = gW2 + seg * 16;
    float v = 0.f;
    #pragma unroll
    for (int k = 0; k < 16; k++) v = fmaf(xs[node][seg * 16 + k], gw[k], v);
    v += __shfl_xor(v, 1);
    v += __shfl_xor(v, 2);
    if (seg == 0) sa.sc[node] = v + gb2[0];
    __syncthreads();
    if (wid == 0) {
        float v0 = sa.sc[lane], v1 = sa.sc[lane + 64];
        float m = fmaxf(v0, v1);
        for (int o = 32; o; o >>= 1) m = fmaxf(m, __shfl_xor(m, o));
        float e0 = __expf(v0 - m), e1 = __expf(v1 - m);
        float ssum = e0 + e1;
        for (int o = 32; o; o >>= 1) ssum += __shfl_xor(ssum, o);
        float inv = frcp(ssum);
        sa.sc[lane] = e0 * inv;
        sa.sc[lane + 64] = e1 * inv;
    }
    __syncthreads();
    int d2 = t & 63, ch = t >> 6;
    float p = 0.f;
    #pragma unroll
    for (int i = 0; i < 16; i++) p = fmaf(sa.sc[ch * 16 + i], xs[ch * 16 + i][d2], p);
    sa.part[ch][d2] = p;
    __syncthreads();
    if (t < DD) {
        float pd = 0.f;
        #pragma unroll
        for (int c2 = 0; c2 < 8; c2++) pd += sa.part[c2][t];
        sa.pooled[t] = pd;
    }
    // kpart reduction: 2048 partials -> red2[32][16]
    {
        int j = t & 15, u = t >> 4;   // u in 0..31: (layer, 16-dim group of 4)
        int L = u >> 4, dg = u & 15;
        float s = 0.f;
        #pragma unroll
        for (int dd2 = 0; dd2 < 4; dd2++) {
            int d = dg * 4 + dd2;
            s += kpart[(L * GG * DD + g * DD + d) * 16 + j];
        }
        red2[u][j] = s;
    }
    __syncthreads();
    if (t < 16) {
        float sk = 0.f;
        #pragma unroll
        for (int u2 = 0; u2 < 32; u2++) sk += red2[u2][t];
        float h2 = clsB[t];
        #pragma unroll
        for (int d3 = 0; d3 < DD; d3++) h2 = fmaf(sa.pooled[d3], clsW[d3 * 16 + t], h2);
        float mo = (hb[g * 16 + t] + hb[256 + g * 16 + t] + h2) * (1.f / 3.f);
        float ko = (sk + kpb0[t] + kpb1[t]) * 0.5f;
        red[t] = (mo + ko) * beta[t];
    }
    __syncthreads();
    if (t == 0) {
        float s = 0.f;
        #pragma unroll
        for (int j = 0; j < 16; j++) s += red[j];
        out[g] = s + h0s[0];
    }
}

extern "C" void kernel_launch(void* const* d_in, const int* in_sizes, int n_in,
                              void* d_out, int out_size, void* d_ws, size_t ws_size,
                              hipStream_t stream) {
    const float* x       = (const float*)d_in[0];
    const int*   ei      = (const int*)  d_in[1];
    const float* gcn_W0  = (const float*)d_in[2];
    const float* gcn_b0  = (const float*)d_in[3];
    const float* gcn_W1  = (const float*)d_in[4];
    const float* gcn_b1  = (const float*)d_in[5];
    const float* lp_W0   = (const float*)d_in[6];
    const float* lp_b0   = (const float*)d_in[7];
    const float* lp_W1   = (const float*)d_in[8];
    const float* lp_b1   = (const float*)d_in[9];
    const float* cls_W   = (const float*)d_in[10];
    const float* cls_b   = (const float*)d_in[11];
    const float* kp_W0   = (const float*)d_in[12];
    const float* kp_b0   = (const float*)d_in[13];
    const float* kp_W1   = (const float*)d_in[14];
    const float* kp_b1   = (const float*)d_in[15];
    const float* gate_W0 = (const float*)d_in[16];
    const float* gate_b0 = (const float*)d_in[17];
    const float* gate_W1 = (const float*)d_in[18];
    const float* gate_b1 = (const float*)d_in[19];
    const float* gate_W2 = (const float*)d_in[20];
    const float* gate_b2 = (const float*)d_in[21];
    const float* beta    = (const float*)d_in[22];
    const float* h0s     = (const float*)d_in[23];

    float* ws = (float*)d_ws;
    int* cnt   = (int*)ws;                        // [2048]
    int* csr   = cnt + NNODE;                     // [2048*64]
    float* A   = (float*)(csr + NNODE * CAP);     // xw [131072]
    float* B   = A + NNODE * DD;                  // cur1 [131072]
    float* hb  = B + NNODE * DD;                  // [512] (h0: +0, h1: +256)
    float* kp  = hb + 512;                        // kpart [2][1024*16]

    const int NMEGA = GG * DD + GG + NNODE / 8;   // 1296

    // D1: mega L0 + CSR-build unit
    k_mega<<<NMEGA + 1, 512, 0, stream>>>(
        x, ei, cnt, csr, A, hb, kp,
        gcn_W0, gate_W0, gate_b0, lp_W0, lp_b0, kp_W0);

    // D2: gather L0 -> B (cur1)
    k_gather<<<NNODE / 8, 512, 0, stream>>>(cnt, csr, A, gcn_b0, B);

    // D3: mega L1 (no fill unit)
    k_mega<<<NMEGA, 512, 0, stream>>>(
        B, ei, cnt, csr, A, hb + 256, kp + GG * DD * 16,
        gcn_W1, gate_W1, gate_b1, lp_W1, lp_b1, kp_W1);

    // D4: per-graph gather L1 + final pool + combine
    k_gfin<<<GG, 512, 0, stream>>>(cnt, csr, A, gcn_b1,
                                   gate_W2, gate_b2, cls_W, cls_b,
                                   hb, kp, kp_b0, kp_b1, beta, h0s, (float*)d_out);
}

// Round 9
// 113.455 us; speedup vs baseline: 2.1249x; 1.3347x over previous
//
#include <hip/hip_runtime.h>
#include <math.h>

#define NNODE 2048
#define NEDGE 32768
#define DD 64
#define GG 16
#define NPG 128   // nodes per graph
#define PP 500    // kde grid points
#define QQ 20     // quantiles
#define CAP 64    // adjacency bucket capacity (max in-degree ~35 here)

__device__ __forceinline__ float fexp2(float x) { return __builtin_amdgcn_exp2f(x); }
__device__ __forceinline__ float frcp(float x)  { return __builtin_amdgcn_rcpf(x); }
__device__ __forceinline__ float frsq(float x)  { return __builtin_amdgcn_rsqf(x); }

struct __align__(8) f2 { float x, y; };

struct KdeS { f2 bc[NPG]; f2 cg[512]; float sred[8]; float wtot[8]; float kfv[QQ]; };
struct AttS { float sc[NPG]; float part[8][DD]; float pooled[DD]; };
struct XwS  { float Ws[DD][DD]; float xr[8][DD]; };
struct CsrS { int lcnt[32]; };
union SmemU { KdeS k; AttS a; XwS x; CsrS c; };

// ---------- attention-pool helper (512 threads), input from global ----------
__device__ __forceinline__ void att_pool(AttS& s, const float* __restrict__ xg,
                                         const float* __restrict__ gW, float gb) {
    int t = threadIdx.x, lane = t & 63, wid = t >> 6;
    int node = t >> 2, seg = t & 3;
    const float* row = xg + node * DD + seg * 16;
    const float* gw = gW + seg * 16;
    float v = 0.f;
    #pragma unroll
    for (int k = 0; k < 16; k++) v = fmaf(row[k], gw[k], v);
    v += __shfl_xor(v, 1);
    v += __shfl_xor(v, 2);
    if (seg == 0) s.sc[node] = v + gb;
    __syncthreads();
    if (wid == 0) {
        float v0 = s.sc[lane], v1 = s.sc[lane + 64];
        float m = fmaxf(v0, v1);
        for (int o = 32; o; o >>= 1) m = fmaxf(m, __shfl_xor(m, o));
        float e0 = __expf(v0 - m), e1 = __expf(v1 - m);
        float ssum = e0 + e1;
        for (int o = 32; o; o >>= 1) ssum += __shfl_xor(ssum, o);
        float inv = frcp(ssum);
        s.sc[lane] = e0 * inv;
        s.sc[lane + 64] = e1 * inv;
    }
    __syncthreads();
    int d2 = t & 63, ch = t >> 6;
    const float* base = xg + ch * 16 * DD + d2;
    const float* av = s.sc + ch * 16;
    float p = 0.f;
    #pragma unroll
    for (int i = 0; i < 16; i++) p = fmaf(av[i], base[i * DD], p);
    s.part[ch][d2] = p;
    __syncthreads();
    if (t < DD) {
        float pd = 0.f;
        #pragma unroll
        for (int c2 = 0; c2 < 8; c2++) pd += s.part[c2][t];
        s.pooled[t] = pd;
    }
    __syncthreads();
}

// ---------- mega kernel ----------
// vb<1024: KDE | vb<1040: att-pool+head | vb<1296: xw=x@W (unscaled)
// vb>=1296 (D1 only): parallel CSR build, block owns 32 dst nodes; vb==1296 zeroes ctr
__global__ __launch_bounds__(512) void k_mega(
    const float* __restrict__ xin, const int* __restrict__ ei,
    int* __restrict__ cnt, int* __restrict__ csr, int* __restrict__ ctr,
    float* __restrict__ xwout, float* __restrict__ hbL, float* __restrict__ kpartL,
    const float* __restrict__ gcnW,
    const float* __restrict__ gateW, const float* __restrict__ gateB,
    const float* __restrict__ lpW, const float* __restrict__ lpB,
    const float* __restrict__ kpW) {
    __shared__ SmemU sm;
    int vb = blockIdx.x, t = threadIdx.x, lane = t & 63, wid = t >> 6;

    if (vb < GG * DD) {
        // ================= KDE: one block per (g,d) =================
        int g = vb >> 6, d = vb & 63;
        const float* xg = xin + g * NPG * DD + d;
        float a = 0.f;
        if (t < NPG) a = xg[t * DD];
        if (wid < 2) {
            float mn = a, mx = a, smv = a;
            for (int o = 32; o; o >>= 1) {
                mn = fminf(mn, __shfl_xor(mn, o));
                mx = fmaxf(mx, __shfl_xor(mx, o));
                smv += __shfl_xor(smv, o);
            }
            if (lane == 0) {
                sm.k.sred[wid * 3 + 0] = mn;
                sm.k.sred[wid * 3 + 1] = mx;
                sm.k.sred[wid * 3 + 2] = smv;
            }
        }
        __syncthreads();
        float mn = fminf(sm.k.sred[0], sm.k.sred[3]) - 1e-6f;
        float mx = fmaxf(sm.k.sred[1], sm.k.sred[4]) + 1e-6f;
        float mean = (sm.k.sred[2] + sm.k.sred[5]) * (1.f / 128.f);
        if (wid < 2) {
            float dv = a - mean;
            float sq = dv * dv;
            for (int o = 32; o; o >>= 1) sq += __shfl_xor(sq, o);
            if (lane == 0) sm.k.sred[6 + wid] = sq;
        }
        __syncthreads();
        float var = fmaxf((sm.k.sred[6] + sm.k.sred[7]) * (1.f / 128.f), 0.f);
        float sd = sqrtf(var) + (1e-8f / 3.0f);
        float h = 0.4016648901252554f * sd;          // 1.06 * 128^-0.2 * std
        float A = -0.5f * 1.4426950408889634f * frcp(h * h);
        if (t < NPG) { f2 v; v.x = -2.f * A * a; v.y = A * a * a; sm.k.bc[t] = v; }
        __syncthreads();
        float step = (mx - mn) * (1.f / 499.f);
        float gp = fmaf(step, (float)t, mn);
        float gA = A * gp * gp;
        const float4* bc4 = (const float4*)sm.k.bc;
        float ac0 = 0.f, ac1 = 0.f, ac2 = 0.f, ac3 = 0.f;
        #pragma unroll 4
        for (int j4 = 0; j4 < 64; j4 += 2) {
            float4 p = bc4[j4], q = bc4[j4 + 1];
            ac0 += fexp2(gA + fmaf(p.x, gp, p.y));
            ac1 += fexp2(gA + fmaf(p.z, gp, p.w));
            ac2 += fexp2(gA + fmaf(q.x, gp, q.y));
            ac3 += fexp2(gA + fmaf(q.z, gp, q.w));
        }
        float invnh = frcp(128.f * h * 2.5066282746310002f);
        float dens = (t < PP) ? ((ac0 + ac1) + (ac2 + ac3)) * invnh : 0.f;
        float sc2 = dens;
        for (int o = 1; o < 64; o <<= 1) {
            float u = __shfl_up(sc2, o);
            if (lane >= o) sc2 += u;
        }
        if (lane == 63) sm.k.wtot[wid] = sc2;
        __syncthreads();
        float offs = 0.f, total = 0.f;
        #pragma unroll
        for (int w = 0; w < 8; w++) {
            float wv = sm.k.wtot[w];
            if (w < wid) offs += wv;
            total += wv;
        }
        float c = (offs + sc2) * frcp(fmaxf(total, 1e-8f));
        f2 cgv; cgv.x = (t < PP) ? c : 4.0f; cgv.y = (t < PP) ? gp : 0.f;
        sm.k.cg[t] = cgv;
        __syncthreads();
        int grp = t >> 4, sub = t & 15;
        if (grp < QQ) {
            float qv = (float)grp * (1.f / 19.f);
            float sw0 = 0.f, sw1 = 0.f, sg0 = 0.f, sg1 = 0.f;
            #pragma unroll
            for (int i = 0; i < 32; i += 2) {
                f2 v0 = sm.k.cg[i * 16 + sub];
                f2 v1 = sm.k.cg[(i + 1) * 16 + sub];
                float e0 = fexp2(fabsf(v0.x - qv) * 144.26950408889634f);
                float e1 = fexp2(fabsf(v1.x - qv) * 144.26950408889634f);
                float w0 = frcp(1.f + e0), w1 = frcp(1.f + e1);
                sw0 += w0; sg0 = fmaf(w0, v0.y, sg0);
                sw1 += w1; sg1 = fmaf(w1, v1.y, sg1);
            }
            float sw = sw0 + sw1, sg = sg0 + sg1;
            #pragma unroll
            for (int o = 1; o < 16; o <<= 1) {
                sw += __shfl_xor(sw, o);
                sg += __shfl_xor(sg, o);
            }
            if (sub == 0) sm.k.kfv[grp] = sg * frcp(sw + 1e-8f);
        }
        __syncthreads();
        if (t < 16) {
            float v = 0.f;
            #pragma unroll
            for (int q = 0; q < QQ; q++) v = fmaf(sm.k.kfv[q], kpW[(d * QQ + q) * 16 + t], v);
            kpartL[vb * 16 + t] = v;
        }
    } else if (vb < GG * DD + GG) {
        // ================= attention-pool + linear head =================
        int g = vb - GG * DD;
        att_pool(sm.a, xin + g * NPG * DD, gateW, gateB[0]);
        if (t < 16) {
            float o = lpB[t];
            #pragma unroll
            for (int d2 = 0; d2 < DD; d2++) o = fmaf(sm.a.pooled[d2], lpW[d2 * 16 + t], o);
            hbL[g * 16 + t] = o;
        }
    } else if (vb < GG * DD + GG + NNODE / 8) {
        // ================= xw = x @ W (unscaled): 8 rows per block =================
        int rb = vb - (GG * DD + GG);
        int r0 = rb * 8;
        float4* Wv = (float4*)&sm.x.Ws[0][0];
        const float4* Gv = (const float4*)gcnW;
        Wv[t] = Gv[t];
        Wv[t + 512] = Gv[t + 512];
        sm.x.xr[wid][lane] = xin[(r0 + wid) * DD + lane];
        __syncthreads();
        float s = 0.f;
        #pragma unroll
        for (int k = 0; k < DD; k++) s = fmaf(sm.x.xr[wid][k], sm.x.Ws[k][lane], s);
        xwout[(r0 + wid) * DD + lane] = s;
    } else {
        // ================= parallel CSR build: block owns 32 dst nodes =================
        int k = vb - (GG * DD + GG + NNODE / 8);   // 0..63
        int base = k * 32;
        if (t < 32) sm.c.lcnt[t] = 0;
        if (k == 0 && t >= 32 && t < 48) ctr[t - 32] = 0;   // zero per-graph fin counters
        __syncthreads();
        for (int c = 0; c < NEDGE / 512; c++) {
            int e = c * 512 + t;
            int dstn = ei[NEDGE + e];
            unsigned rel = (unsigned)(dstn - base);
            if (rel < 32u) {
                int s = ei[e];
                int pos = atomicAdd(&sm.c.lcnt[rel], 1);
                if (pos < CAP) csr[dstn * CAP + pos] = s;
            }
        }
        __syncthreads();
        if (t < 32) cnt[base + t] = sm.c.lcnt[t];
    }
}

// ---------- gather L0: cur[n] = dinv[n]*(sum_s dinv[s]*xw[s] + dinv[n]*xw[n]) + b ----------
__global__ __launch_bounds__(512) void k_gather(const int* __restrict__ cnt,
                                                const int* __restrict__ csr,
                                                const float* __restrict__ xw,
                                                const float* __restrict__ bvec,
                                                float* __restrict__ cur) {
    int t = threadIdx.x, lane = t & 63, wid = t >> 6;
    int n = blockIdx.x * 8 + wid;
    int ecn = cnt[n];
    int ec = ecn > CAP ? CAP : ecn;
    const int* lst = csr + n * CAP;
    float sum0 = 0.f, sum1 = 0.f;
    int j = 0;
    for (; j + 2 <= ec; j += 2) {
        int s0 = lst[j], s1 = lst[j + 1];
        sum0 = fmaf(frsq((float)cnt[s0] + 1.f), xw[s0 * DD + lane], sum0);
        sum1 = fmaf(frsq((float)cnt[s1] + 1.f), xw[s1 * DD + lane], sum1);
    }
    if (j < ec) {
        int s0 = lst[j];
        sum0 = fmaf(frsq((float)cnt[s0] + 1.f), xw[s0 * DD + lane], sum0);
    }
    float di = frsq((float)ecn + 1.f);
    cur[n * DD + lane] = di * ((sum0 + sum1) + di * xw[n * DD + lane]) + bvec[lane];
}

// ---------- gather L1 + per-graph last-block fin ----------
__global__ __launch_bounds__(512) void k_gfin2(
    const int* __restrict__ cnt, const int* __restrict__ csr,
    const float* __restrict__ xw, const float* __restrict__ gcn_b1,
    int* __restrict__ ctr, float* __restrict__ B,
    const float* __restrict__ gW2, const float* __restrict__ gb2,
    const float* __restrict__ clsW, const float* __restrict__ clsB,
    const float* __restrict__ hb, const float* __restrict__ kpart,
    const float* __restrict__ kpb0, const float* __restrict__ kpb1,
    const float* __restrict__ beta, const float* __restrict__ h0s,
    float* __restrict__ out) {
    __shared__ AttS sa;
    __shared__ float red2[32][16];
    __shared__ float red[16];
    __shared__ int islast;
    int t = threadIdx.x, lane = t & 63, wid = t >> 6;

    // ---- gather this block's 8 nodes -> B ----
    {
        int n = blockIdx.x * 8 + wid;
        int ecn = cnt[n];
        int ec = ecn > CAP ? CAP : ecn;
        const int* lst = csr + n * CAP;
        float sum0 = 0.f, sum1 = 0.f;
        int j = 0;
        for (; j + 2 <= ec; j += 2) {
            int s0 = lst[j], s1 = lst[j + 1];
            sum0 = fmaf(frsq((float)cnt[s0] + 1.f), xw[s0 * DD + lane], sum0);
            sum1 = fmaf(frsq((float)cnt[s1] + 1.f), xw[s1 * DD + lane], sum1);
        }
        if (j < ec) {
            int s0 = lst[j];
            sum0 = fmaf(frsq((float)cnt[s0] + 1.f), xw[s0 * DD + lane], sum0);
        }
        float di = frsq((float)ecn + 1.f);
        B[n * DD + lane] = di * ((sum0 + sum1) + di * xw[n * DD + lane]) + gcn_b1[lane];
    }

    // ---- last block of each graph continues into fin ----
    __threadfence();     // release: publish B rows device-wide
    if (t == 0) {
        int old = __hip_atomic_fetch_add(&ctr[blockIdx.x >> 4], 1,
                                         __ATOMIC_ACQ_REL, __HIP_MEMORY_SCOPE_AGENT);
        islast = (old == 15) ? 1 : 0;
    }
    __syncthreads();
    if (!islast) return;
    __threadfence();     // acquire: invalidate before reading other blocks' B rows
    int g = blockIdx.x >> 4;

    att_pool(sa, B + g * NPG * DD, gW2, gb2[0]);
    // kpart reduction: 2*64 partial vectors -> red2[32][16]
    {
        int j = t & 15, u = t >> 4;   // u: (layer<<4)|dim-group
        int L = u >> 4, dg = u & 15;
        float s = 0.f;
        #pragma unroll
        for (int dd2 = 0; dd2 < 4; dd2++) {
            int d = dg * 4 + dd2;
            s += kpart[(L * GG * DD + g * DD + d) * 16 + j];
        }
        red2[u][j] = s;
    }
    __syncthreads();
    if (t < 16) {
        float sk = 0.f;
        #pragma unroll
        for (int u2 = 0; u2 < 32; u2++) sk += red2[u2][t];
        float h2 = clsB[t];
        #pragma unroll
        for (int d3 = 0; d3 < DD; d3++) h2 = fmaf(sa.pooled[d3], clsW[d3 * 16 + t], h2);
        float mo = (hb[g * 16 + t] + hb[256 + g * 16 + t] + h2) * (1.f / 3.f);
        float ko = (sk + kpb0[t] + kpb1[t]) * 0.5f;
        red[t] = (mo + ko) * beta[t];
    }
    __syncthreads();
    if (t == 0) {
        float s = 0.f;
        #pragma unroll
        for (int j = 0; j < 16; j++) s += red[j];
        out[g] = s + h0s[0];
    }
}

extern "C" void kernel_launch(void* const* d_in, const int* in_sizes, int n_in,
                              void* d_out, int out_size, void* d_ws, size_t ws_size,
                              hipStream_t stream) {
    const float* x       = (const float*)d_in[0];
    const int*   ei      = (const int*)  d_in[1];
    const float* gcn_W0  = (const float*)d_in[2];
    const float* gcn_b0  = (const float*)d_in[3];
    const float* gcn_W1  = (const float*)d_in[4];
    const float* gcn_b1  = (const float*)d_in[5];
    const float* lp_W0   = (const float*)d_in[6];
    const float* lp_b0   = (const float*)d_in[7];
    const float* lp_W1   = (const float*)d_in[8];
    const float* lp_b1   = (const float*)d_in[9];
    const float* cls_W   = (const float*)d_in[10];
    const float* cls_b   = (const float*)d_in[11];
    const float* kp_W0   = (const float*)d_in[12];
    const float* kp_b0   = (const float*)d_in[13];
    const float* kp_W1   = (const float*)d_in[14];
    const float* kp_b1   = (const float*)d_in[15];
    const float* gate_W0 = (const float*)d_in[16];
    const float* gate_b0 = (const float*)d_in[17];
    const float* gate_W1 = (const float*)d_in[18];
    const float* gate_b1 = (const float*)d_in[19];
    const float* gate_W2 = (const float*)d_in[20];
    const float* gate_b2 = (const float*)d_in[21];
    const float* beta    = (const float*)d_in[22];
    const float* h0s     = (const float*)d_in[23];

    float* ws = (float*)d_ws;
    int* cnt   = (int*)ws;                        // [2048]
    int* csr   = cnt + NNODE;                     // [2048*64]
    float* A   = (float*)(csr + NNODE * CAP);     // xw [131072]
    float* B   = A + NNODE * DD;                  // cur [131072]
    float* hb  = B + NNODE * DD;                  // [512] (h0: +0, h1: +256)
    float* kp  = hb + 512;                        // kpart [2][1024*16]
    int* ctr   = (int*)(kp + 2 * GG * DD * 16);   // [16] per-graph fin counters

    const int NMEGA = GG * DD + GG + NNODE / 8;   // 1296

    // D1: mega L0 + 64 parallel CSR-build blocks (also zero ctr)
    k_mega<<<NMEGA + 64, 512, 0, stream>>>(
        x, ei, cnt, csr, ctr, A, hb, kp,
        gcn_W0, gate_W0, gate_b0, lp_W0, lp_b0, kp_W0);

    // D2: gather L0 -> B (cur1)
    k_gather<<<NNODE / 8, 512, 0, stream>>>(cnt, csr, A, gcn_b0, B);

    // D3: mega L1
    k_mega<<<NMEGA, 512, 0, stream>>>(
        B, ei, cnt, csr, ctr, A, hb + 256, kp + GG * DD * 16,
        gcn_W1, gate_W1, gate_b1, lp_W1, lp_b1, kp_W1);

    // D4: gather L1 + per-graph last-block fin
    k_gfin2<<<NNODE / 8, 512, 0, stream>>>(cnt, csr, A, gcn_b1, ctr, B,
                                           gate_W2, gate_b2, cls_W, cls_b,
                                           hb, kp, kp_b0, kp_b1, beta, h0s,
                                           (float*)d_out);
}

// Round 10
// 72.377 us; speedup vs baseline: 3.3308x; 1.5676x over previous
//
#include <hip/hip_runtime.h>
#include <math.h>

#define NNODE 2048
#define NEDGE 32768
#define DD 64
#define GG 16
#define NPG 128   // nodes per graph
#define PP 500    // kde grid points
#define QQ 20     // quantiles
#define CAP 64    // adjacency bucket capacity (max in-degree ~35 here)

__device__ __forceinline__ float fexp2(float x) { return __builtin_amdgcn_exp2f(x); }
__device__ __forceinline__ float frcp(float x)  { return __builtin_amdgcn_rcpf(x); }
__device__ __forceinline__ float frsq(float x)  { return __builtin_amdgcn_rsqf(x); }

struct __align__(8) f2 { float x, y; };

struct KdeS { f2 bc[NPG]; f2 cg[512]; float sred[8]; float wtot[8]; float kfv[QQ]; };
struct AttS { float sc[NPG]; float part[8][DD]; float pooled[DD]; };
struct XwS  { float Ws[DD][DD]; float xr[8][DD]; };
struct CsrS { int lcnt[32]; };
union SmemU { KdeS k; AttS a; XwS x; CsrS c; };

// ---------- attention-pool helper (512 threads), input from global ----------
__device__ __forceinline__ void att_pool(AttS& s, const float* __restrict__ xg,
                                         const float* __restrict__ gW, float gb) {
    int t = threadIdx.x, lane = t & 63, wid = t >> 6;
    int node = t >> 2, seg = t & 3;
    const float* row = xg + node * DD + seg * 16;
    const float* gw = gW + seg * 16;
    float v = 0.f;
    #pragma unroll
    for (int k = 0; k < 16; k++) v = fmaf(row[k], gw[k], v);
    v += __shfl_xor(v, 1);
    v += __shfl_xor(v, 2);
    if (seg == 0) s.sc[node] = v + gb;
    __syncthreads();
    if (wid == 0) {
        float v0 = s.sc[lane], v1 = s.sc[lane + 64];
        float m = fmaxf(v0, v1);
        for (int o = 32; o; o >>= 1) m = fmaxf(m, __shfl_xor(m, o));
        float e0 = __expf(v0 - m), e1 = __expf(v1 - m);
        float ssum = e0 + e1;
        for (int o = 32; o; o >>= 1) ssum += __shfl_xor(ssum, o);
        float inv = frcp(ssum);
        s.sc[lane] = e0 * inv;
        s.sc[lane + 64] = e1 * inv;
    }
    __syncthreads();
    int d2 = t & 63, ch = t >> 6;
    const float* base = xg + ch * 16 * DD + d2;
    const float* av = s.sc + ch * 16;
    float p = 0.f;
    #pragma unroll
    for (int i = 0; i < 16; i++) p = fmaf(av[i], base[i * DD], p);
    s.part[ch][d2] = p;
    __syncthreads();
    if (t < DD) {
        float pd = 0.f;
        #pragma unroll
        for (int c2 = 0; c2 < 8; c2++) pd += s.part[c2][t];
        s.pooled[t] = pd;
    }
    __syncthreads();
}

// ---------- mega kernel ----------
// vb<1024: KDE | vb<1040: att-pool+head | vb<1296: xw=x@W (unscaled)
// vb>=1296 (D1 only): parallel CSR build, block owns 32 dst nodes
__global__ __launch_bounds__(512) void k_mega(
    const float* __restrict__ xin, const int* __restrict__ ei,
    int* __restrict__ cnt, int* __restrict__ csr,
    float* __restrict__ xwout, float* __restrict__ hbL, float* __restrict__ kpartL,
    const float* __restrict__ gcnW,
    const float* __restrict__ gateW, const float* __restrict__ gateB,
    const float* __restrict__ lpW, const float* __restrict__ lpB,
    const float* __restrict__ kpW) {
    __shared__ SmemU sm;
    int vb = blockIdx.x, t = threadIdx.x, lane = t & 63, wid = t >> 6;

    if (vb < GG * DD) {
        // ================= KDE: one block per (g,d) =================
        int g = vb >> 6, d = vb & 63;
        const float* xg = xin + g * NPG * DD + d;
        float a = 0.f;
        if (t < NPG) a = xg[t * DD];
        if (wid < 2) {
            float mn = a, mx = a, smv = a;
            for (int o = 32; o; o >>= 1) {
                mn = fminf(mn, __shfl_xor(mn, o));
                mx = fmaxf(mx, __shfl_xor(mx, o));
                smv += __shfl_xor(smv, o);
            }
            if (lane == 0) {
                sm.k.sred[wid * 3 + 0] = mn;
                sm.k.sred[wid * 3 + 1] = mx;
                sm.k.sred[wid * 3 + 2] = smv;
            }
        }
        __syncthreads();
        float mn = fminf(sm.k.sred[0], sm.k.sred[3]) - 1e-6f;
        float mx = fmaxf(sm.k.sred[1], sm.k.sred[4]) + 1e-6f;
        float mean = (sm.k.sred[2] + sm.k.sred[5]) * (1.f / 128.f);
        if (wid < 2) {
            float dv = a - mean;
            float sq = dv * dv;
            for (int o = 32; o; o >>= 1) sq += __shfl_xor(sq, o);
            if (lane == 0) sm.k.sred[6 + wid] = sq;
        }
        __syncthreads();
        float var = fmaxf((sm.k.sred[6] + sm.k.sred[7]) * (1.f / 128.f), 0.f);
        float sd = sqrtf(var) + (1e-8f / 3.0f);
        float h = 0.4016648901252554f * sd;          // 1.06 * 128^-0.2 * std
        float A = -0.5f * 1.4426950408889634f * frcp(h * h);
        if (t < NPG) { f2 v; v.x = -2.f * A * a; v.y = A * a * a; sm.k.bc[t] = v; }
        __syncthreads();
        float step = (mx - mn) * (1.f / 499.f);
        float gp = fmaf(step, (float)t, mn);
        float gA = A * gp * gp;
        const float4* bc4 = (const float4*)sm.k.bc;
        float ac0 = 0.f, ac1 = 0.f, ac2 = 0.f, ac3 = 0.f;
        #pragma unroll 4
        for (int j4 = 0; j4 < 64; j4 += 2) {
            float4 p = bc4[j4], q = bc4[j4 + 1];
            ac0 += fexp2(gA + fmaf(p.x, gp, p.y));
            ac1 += fexp2(gA + fmaf(p.z, gp, p.w));
            ac2 += fexp2(gA + fmaf(q.x, gp, q.y));
            ac3 += fexp2(gA + fmaf(q.z, gp, q.w));
        }
        float invnh = frcp(128.f * h * 2.5066282746310002f);
        float dens = (t < PP) ? ((ac0 + ac1) + (ac2 + ac3)) * invnh : 0.f;
        float sc2 = dens;
        for (int o = 1; o < 64; o <<= 1) {
            float u = __shfl_up(sc2, o);
            if (lane >= o) sc2 += u;
        }
        if (lane == 63) sm.k.wtot[wid] = sc2;
        __syncthreads();
        float offs = 0.f, total = 0.f;
        #pragma unroll
        for (int w = 0; w < 8; w++) {
            float wv = sm.k.wtot[w];
            if (w < wid) offs += wv;
            total += wv;
        }
        float c = (offs + sc2) * frcp(fmaxf(total, 1e-8f));
        f2 cgv; cgv.x = (t < PP) ? c : 4.0f; cgv.y = (t < PP) ? gp : 0.f;
        sm.k.cg[t] = cgv;
        __syncthreads();
        int grp = t >> 4, sub = t & 15;
        if (grp < QQ) {
            float qv = (float)grp * (1.f / 19.f);
            float sw0 = 0.f, sw1 = 0.f, sg0 = 0.f, sg1 = 0.f;
            #pragma unroll
            for (int i = 0; i < 32; i += 2) {
                f2 v0 = sm.k.cg[i * 16 + sub];
                f2 v1 = sm.k.cg[(i + 1) * 16 + sub];
                float e0 = fexp2(fabsf(v0.x - qv) * 144.26950408889634f);
                float e1 = fexp2(fabsf(v1.x - qv) * 144.26950408889634f);
                float w0 = frcp(1.f + e0), w1 = frcp(1.f + e1);
                sw0 += w0; sg0 = fmaf(w0, v0.y, sg0);
                sw1 += w1; sg1 = fmaf(w1, v1.y, sg1);
            }
            float sw = sw0 + sw1, sg = sg0 + sg1;
            #pragma unroll
            for (int o = 1; o < 16; o <<= 1) {
                sw += __shfl_xor(sw, o);
                sg += __shfl_xor(sg, o);
            }
            if (sub == 0) sm.k.kfv[grp] = sg * frcp(sw + 1e-8f);
        }
        __syncthreads();
        if (t < 16) {
            float v = 0.f;
            #pragma unroll
            for (int q = 0; q < QQ; q++) v = fmaf(sm.k.kfv[q], kpW[(d * QQ + q) * 16 + t], v);
            kpartL[vb * 16 + t] = v;
        }
    } else if (vb < GG * DD + GG) {
        // ================= attention-pool + linear head =================
        int g = vb - GG * DD;
        att_pool(sm.a, xin + g * NPG * DD, gateW, gateB[0]);
        if (t < 16) {
            float o = lpB[t];
            #pragma unroll
            for (int d2 = 0; d2 < DD; d2++) o = fmaf(sm.a.pooled[d2], lpW[d2 * 16 + t], o);
            hbL[g * 16 + t] = o;
        }
    } else if (vb < GG * DD + GG + NNODE / 8) {
        // ================= xw = x @ W (unscaled): 8 rows per block =================
        int rb = vb - (GG * DD + GG);
        int r0 = rb * 8;
        float4* Wv = (float4*)&sm.x.Ws[0][0];
        const float4* Gv = (const float4*)gcnW;
        Wv[t] = Gv[t];
        Wv[t + 512] = Gv[t + 512];
        sm.x.xr[wid][lane] = xin[(r0 + wid) * DD + lane];
        __syncthreads();
        float s = 0.f;
        #pragma unroll
        for (int k = 0; k < DD; k++) s = fmaf(sm.x.xr[wid][k], sm.x.Ws[k][lane], s);
        xwout[(r0 + wid) * DD + lane] = s;
    } else {
        // ================= parallel CSR build: block owns 32 dst nodes =================
        int k = vb - (GG * DD + GG + NNODE / 8);   // 0..63
        int base = k * 32;
        if (t < 32) sm.c.lcnt[t] = 0;
        __syncthreads();
        for (int c = 0; c < NEDGE / 512; c++) {
            int e = c * 512 + t;
            int dstn = ei[NEDGE + e];
            unsigned rel = (unsigned)(dstn - base);
            if (rel < 32u) {
                int s = ei[e];
                int pos = atomicAdd(&sm.c.lcnt[rel], 1);
                if (pos < CAP) csr[dstn * CAP + pos] = s;
            }
        }
        __syncthreads();
        if (t < 32) cnt[base + t] = sm.c.lcnt[t];
    }
}

// ---------- gather: cur[n] = dinv[n]*(sum_s dinv[s]*xw[s] + dinv[n]*xw[n]) + b ----------
__global__ __launch_bounds__(512) void k_gather(const int* __restrict__ cnt,
                                                const int* __restrict__ csr,
                                                const float* __restrict__ xw,
                                                const float* __restrict__ bvec,
                                                float* __restrict__ cur) {
    int t = threadIdx.x, lane = t & 63, wid = t >> 6;
    int n = blockIdx.x * 8 + wid;
    int ecn = cnt[n];
    int ec = ecn > CAP ? CAP : ecn;
    const int* lst = csr + n * CAP;
    float sum0 = 0.f, sum1 = 0.f;
    int j = 0;
    for (; j + 2 <= ec; j += 2) {
        int s0 = lst[j], s1 = lst[j + 1];
        sum0 = fmaf(frsq((float)cnt[s0] + 1.f), xw[s0 * DD + lane], sum0);
        sum1 = fmaf(frsq((float)cnt[s1] + 1.f), xw[s1 * DD + lane], sum1);
    }
    if (j < ec) {
        int s0 = lst[j];
        sum0 = fmaf(frsq((float)cnt[s0] + 1.f), xw[s0 * DD + lane], sum0);
    }
    float di = frsq((float)ecn + 1.f);
    cur[n * DD + lane] = di * ((sum0 + sum1) + di * xw[n * DD + lane]) + bvec[lane];
}

// ---------- fin: att-pool(cur2) + cls head + kpart reduction + combine ----------
__global__ __launch_bounds__(512) void k_fin(const float* __restrict__ cur2,
    const float* __restrict__ gW2, const float* __restrict__ gb2,
    const float* __restrict__ clsW, const float* __restrict__ clsB,
    const float* __restrict__ hb, const float* __restrict__ kpart,
    const float* __restrict__ kpb0, const float* __restrict__ kpb1,
    const float* __restrict__ beta, const float* __restrict__ h0s,
    float* __restrict__ out) {
    __shared__ AttS sa;
    __shared__ float red2[32][16];
    __shared__ float red[16];
    int g = blockIdx.x, t = threadIdx.x;
    att_pool(sa, cur2 + g * NPG * DD, gW2, gb2[0]);
    // kpart reduction: 2 layers x 64 partial vectors -> red2[32][16]
    {
        int j = t & 15, u = t >> 4;   // u: (layer<<4)|dim-group
        int L = u >> 4, dg = u & 15;
        float s = 0.f;
        #pragma unroll
        for (int dd2 = 0; dd2 < 4; dd2++) {
            int d = dg * 4 + dd2;
            s += kpart[(L * GG * DD + g * DD + d) * 16 + j];
        }
        red2[u][j] = s;
    }
    __syncthreads();
    if (t < 16) {
        float sk = 0.f;
        #pragma unroll
        for (int u2 = 0; u2 < 32; u2++) sk += red2[u2][t];
        float h2 = clsB[t];
        #pragma unroll
        for (int d3 = 0; d3 < DD; d3++) h2 = fmaf(sa.pooled[d3], clsW[d3 * 16 + t], h2);
        float mo = (hb[g * 16 + t] + hb[256 + g * 16 + t] + h2) * (1.f / 3.f);
        float ko = (sk + kpb0[t] + kpb1[t]) * 0.5f;
        red[t] = (mo + ko) * beta[t];
    }
    __syncthreads();
    if (t == 0) {
        float s = 0.f;
        #pragma unroll
        for (int j = 0; j < 16; j++) s += red[j];
        out[g] = s + h0s[0];
    }
}

extern "C" void kernel_launch(void* const* d_in, const int* in_sizes, int n_in,
                              void* d_out, int out_size, void* d_ws, size_t ws_size,
                              hipStream_t stream) {
    const float* x       = (const float*)d_in[0];
    const int*   ei      = (const int*)  d_in[1];
    const float* gcn_W0  = (const float*)d_in[2];
    const float* gcn_b0  = (const float*)d_in[3];
    const float* gcn_W1  = (const float*)d_in[4];
    const float* gcn_b1  = (const float*)d_in[5];
    const float* lp_W0   = (const float*)d_in[6];
    const float* lp_b0   = (const float*)d_in[7];
    const float* lp_W1   = (const float*)d_in[8];
    const float* lp_b1   = (const float*)d_in[9];
    const float* cls_W   = (const float*)d_in[10];
    const float* cls_b   = (const float*)d_in[11];
    const float* kp_W0   = (const float*)d_in[12];
    const float* kp_b0   = (const float*)d_in[13];
    const float* kp_W1   = (const float*)d_in[14];
    const float* kp_b1   = (const float*)d_in[15];
    const float* gate_W0 = (const float*)d_in[16];
    const float* gate_b0 = (const float*)d_in[17];
    const float* gate_W1 = (const float*)d_in[18];
    const float* gate_b1 = (const float*)d_in[19];
    const float* gate_W2 = (const float*)d_in[20];
    const float* gate_b2 = (const float*)d_in[21];
    const float* beta    = (const float*)d_in[22];
    const float* h0s     = (const float*)d_in[23];

    float* ws = (float*)d_ws;
    int* cnt   = (int*)ws;                        // [2048]
    int* csr   = cnt + NNODE;                     // [2048*64]
    float* A   = (float*)(csr + NNODE * CAP);     // xw [131072]
    float* B   = A + NNODE * DD;                  // cur [131072]
    float* hb  = B + NNODE * DD;                  // [512] (h0: +0, h1: +256)
    float* kp  = hb + 512;                        // kpart [2][1024*16]

    const int NMEGA = GG * DD + GG + NNODE / 8;   // 1296

    // D1: mega L0 + 64 parallel CSR-build blocks
    k_mega<<<NMEGA + 64, 512, 0, stream>>>(
        x, ei, cnt, csr, A, hb, kp,
        gcn_W0, gate_W0, gate_b0, lp_W0, lp_b0, kp_W0);

    // D2: gather L0 -> B (cur1)
    k_gather<<<NNODE / 8, 512, 0, stream>>>(cnt, csr, A, gcn_b0, B);

    // D3: mega L1
    k_mega<<<NMEGA, 512, 0, stream>>>(
        B, ei, cnt, csr, A, hb + 256, kp + GG * DD * 16,
        gcn_W1, gate_W1, gate_b1, lp_W1, lp_b1, kp_W1);

    // D4: gather L1 -> B (cur2)
    k_gather<<<NNODE / 8, 512, 0, stream>>>(cnt, csr, A, gcn_b1, B);

    // D5: final pool + combine
    k_fin<<<GG, 512, 0, stream>>>(B, gate_W2, gate_b2, cls_W, cls_b,
                                  hb, kp, kp_b0, kp_b1, beta, h0s, (float*)d_out);
}

// Round 11
// 58.476 us; speedup vs baseline: 4.1226x; 1.2377x over previous
//
#include <hip/hip_runtime.h>
#include <math.h>

#define NNODE 2048
#define NEDGE 32768
#define DD 64
#define GG 16
#define NPG 128   // nodes per graph
#define PP 500    // kde grid points
#define QQ 20     // quantiles
#define CAP 64    // adjacency bucket capacity (max in-degree ~35 here)

__device__ __forceinline__ float fexp2(float x) { return __builtin_amdgcn_exp2f(x); }
__device__ __forceinline__ float frcp(float x)  { return __builtin_amdgcn_rcpf(x); }
__device__ __forceinline__ float frsq(float x)  { return __builtin_amdgcn_rsqf(x); }

struct __align__(8) f2 { float x, y; };

struct KdeS { f2 bc[NPG]; f2 cg[512]; float sred[8]; float wtot[8]; float kfv[QQ]; };
struct AttS { float sc[NPG]; float part[8][DD]; float pooled[DD]; };
struct XwS  { float Ws[DD][DD]; float xr[8][DD]; };
struct CsrS { int lcnt[32]; };
union SmemU { KdeS k; AttS a; XwS x; CsrS c; };

// ---------- attention-pool helper (512 threads), input from global ----------
__device__ __forceinline__ void att_pool(AttS& s, const float* __restrict__ xg,
                                         const float* __restrict__ gW, float gb) {
    int t = threadIdx.x, lane = t & 63, wid = t >> 6;
    int node = t >> 2, seg = t & 3;
    const float* row = xg + node * DD + seg * 16;
    const float* gw = gW + seg * 16;
    float v = 0.f;
    #pragma unroll
    for (int k = 0; k < 16; k++) v = fmaf(row[k], gw[k], v);
    v += __shfl_xor(v, 1);
    v += __shfl_xor(v, 2);
    if (seg == 0) s.sc[node] = v + gb;
    __syncthreads();
    if (wid == 0) {
        float v0 = s.sc[lane], v1 = s.sc[lane + 64];
        float m = fmaxf(v0, v1);
        for (int o = 32; o; o >>= 1) m = fmaxf(m, __shfl_xor(m, o));
        float e0 = __expf(v0 - m), e1 = __expf(v1 - m);
        float ssum = e0 + e1;
        for (int o = 32; o; o >>= 1) ssum += __shfl_xor(ssum, o);
        float inv = frcp(ssum);
        s.sc[lane] = e0 * inv;
        s.sc[lane + 64] = e1 * inv;
    }
    __syncthreads();
    int d2 = t & 63, ch = t >> 6;
    const float* base = xg + ch * 16 * DD + d2;
    const float* av = s.sc + ch * 16;
    float p = 0.f;
    #pragma unroll
    for (int i = 0; i < 16; i++) p = fmaf(av[i], base[i * DD], p);
    s.part[ch][d2] = p;
    __syncthreads();
    if (t < DD) {
        float pd = 0.f;
        #pragma unroll
        for (int c2 = 0; c2 < 8; c2++) pd += s.part[c2][t];
        s.pooled[t] = pd;
    }
    __syncthreads();
}

// ---------- mega kernel ----------
// vb<csrBlocks: CSR build (D1 only, FIRST so it overlaps round-1 compute blocks)
// then u=vb-csrBlocks: u<1024 KDE | u<1040 att-pool+head | u<1296 xw=x@W (unscaled)
__global__ __launch_bounds__(512) void k_mega(
    const float* __restrict__ xin, const int* __restrict__ ei,
    int* __restrict__ cnt, int* __restrict__ csr, float* __restrict__ dinvF,
    float* __restrict__ xwout, float* __restrict__ hbL, float* __restrict__ kpartL,
    const float* __restrict__ gcnW,
    const float* __restrict__ gateW, const float* __restrict__ gateB,
    const float* __restrict__ lpW, const float* __restrict__ lpB,
    const float* __restrict__ kpW, int csrBlocks) {
    __shared__ SmemU sm;
    int vb = blockIdx.x, t = threadIdx.x, lane = t & 63, wid = t >> 6;

    if (vb < csrBlocks) {
        // ================= parallel CSR build: block owns 32 dst nodes =================
        int base = vb * 32;
        if (t < 32) sm.c.lcnt[t] = 0;
        __syncthreads();
        for (int c = 0; c < NEDGE / 512; c++) {
            int e = c * 512 + t;
            int dstn = ei[NEDGE + e];
            unsigned rel = (unsigned)(dstn - base);
            if (rel < 32u) {
                int s = ei[e];
                int pos = atomicAdd(&sm.c.lcnt[rel], 1);
                if (pos < CAP) csr[dstn * CAP + pos] = s;
            }
        }
        __syncthreads();
        if (t < 32) {
            int c = sm.c.lcnt[t];
            cnt[base + t] = c;
            dinvF[base + t] = frsq((float)c + 1.0f);
        }
        return;
    }
    int u = vb - csrBlocks;

    if (u < GG * DD) {
        // ================= KDE: one block per (g,d) =================
        int g = u >> 6, d = u & 63;
        const float* xg = xin + g * NPG * DD + d;
        float a = 0.f;
        if (t < NPG) a = xg[t * DD];
        // one-pass stats: mn, mx, sum, sumsq (waves 0,1)
        if (wid < 2) {
            float mn = a, mx = a, smv = a, sq = a * a;
            for (int o = 32; o; o >>= 1) {
                mn = fminf(mn, __shfl_xor(mn, o));
                mx = fmaxf(mx, __shfl_xor(mx, o));
                smv += __shfl_xor(smv, o);
                sq += __shfl_xor(sq, o);
            }
            if (lane == 0) {
                sm.k.sred[wid * 4 + 0] = mn;
                sm.k.sred[wid * 4 + 1] = mx;
                sm.k.sred[wid * 4 + 2] = smv;
                sm.k.sred[wid * 4 + 3] = sq;
            }
        }
        __syncthreads();
        float mn = fminf(sm.k.sred[0], sm.k.sred[4]) - 1e-6f;
        float mx = fmaxf(sm.k.sred[1], sm.k.sred[5]) + 1e-6f;
        float mean = (sm.k.sred[2] + sm.k.sred[6]) * (1.f / 128.f);
        float ex2 = (sm.k.sred[3] + sm.k.sred[7]) * (1.f / 128.f);
        float var = fmaxf(ex2 - mean * mean, 0.f);
        float sd = sqrtf(var) + (1e-8f / 3.0f);
        float h = 0.4016648901252554f * sd;          // 1.06 * 128^-0.2 * std
        float A = -0.5f * 1.4426950408889634f * frcp(h * h);
        if (t < NPG) { f2 v; v.x = -2.f * A * a; v.y = A * a * a; sm.k.bc[t] = v; }
        __syncthreads();
        float step = (mx - mn) * (1.f / 499.f);
        float gp = fmaf(step, (float)t, mn);
        float gA = A * gp * gp;
        const float4* bc4 = (const float4*)sm.k.bc;
        float ac0 = 0.f, ac1 = 0.f, ac2 = 0.f, ac3 = 0.f;
        #pragma unroll 4
        for (int j4 = 0; j4 < 64; j4 += 2) {
            float4 p = bc4[j4], q = bc4[j4 + 1];
            ac0 += fexp2(gA + fmaf(p.x, gp, p.y));
            ac1 += fexp2(gA + fmaf(p.z, gp, p.w));
            ac2 += fexp2(gA + fmaf(q.x, gp, q.y));
            ac3 += fexp2(gA + fmaf(q.z, gp, q.w));
        }
        float invnh = frcp(128.f * h * 2.5066282746310002f);
        float dens = (t < PP) ? ((ac0 + ac1) + (ac2 + ac3)) * invnh : 0.f;
        float sc2 = dens;
        for (int o = 1; o < 64; o <<= 1) {
            float uu = __shfl_up(sc2, o);
            if (lane >= o) sc2 += uu;
        }
        if (lane == 63) sm.k.wtot[wid] = sc2;
        __syncthreads();
        float offs = 0.f, total = 0.f;
        #pragma unroll
        for (int w = 0; w < 8; w++) {
            float wv = sm.k.wtot[w];
            if (w < wid) offs += wv;
            total += wv;
        }
        float c = (offs + sc2) * frcp(fmaxf(total, 1e-8f));
        f2 cgv; cgv.x = (t < PP) ? c : 4.0f; cgv.y = (t < PP) ? gp : 0.f;
        sm.k.cg[t] = cgv;
        __syncthreads();
        int grp = t >> 4, sub = t & 15;
        if (grp < QQ) {
            float qv = (float)grp * (1.f / 19.f);
            float sw0 = 0.f, sw1 = 0.f, sg0 = 0.f, sg1 = 0.f;
            #pragma unroll
            for (int i = 0; i < 32; i += 2) {
                f2 v0 = sm.k.cg[i * 16 + sub];
                f2 v1 = sm.k.cg[(i + 1) * 16 + sub];
                float e0 = fexp2(fabsf(v0.x - qv) * 144.26950408889634f);
                float e1 = fexp2(fabsf(v1.x - qv) * 144.26950408889634f);
                float w0 = frcp(1.f + e0), w1 = frcp(1.f + e1);
                sw0 += w0; sg0 = fmaf(w0, v0.y, sg0);
                sw1 += w1; sg1 = fmaf(w1, v1.y, sg1);
            }
            float sw = sw0 + sw1, sg = sg0 + sg1;
            #pragma unroll
            for (int o = 1; o < 16; o <<= 1) {
                sw += __shfl_xor(sw, o);
                sg += __shfl_xor(sg, o);
            }
            if (sub == 0) sm.k.kfv[grp] = sg * frcp(sw + 1e-8f);
        }
        __syncthreads();
        if (t < 16) {
            float v = 0.f;
            #pragma unroll
            for (int q = 0; q < QQ; q++) v = fmaf(sm.k.kfv[q], kpW[(d * QQ + q) * 16 + t], v);
            kpartL[u * 16 + t] = v;
        }
    } else if (u < GG * DD + GG) {
        // ================= attention-pool + linear head =================
        int g = u - GG * DD;
        att_pool(sm.a, xin + g * NPG * DD, gateW, gateB[0]);
        if (t < 16) {
            float o = lpB[t];
            #pragma unroll
            for (int d2 = 0; d2 < DD; d2++) o = fmaf(sm.a.pooled[d2], lpW[d2 * 16 + t], o);
            hbL[g * 16 + t] = o;
        }
    } else {
        // ================= xw = x @ W (unscaled): 8 rows per block =================
        int rb = u - (GG * DD + GG);
        int r0 = rb * 8;
        float4* Wv = (float4*)&sm.x.Ws[0][0];
        const float4* Gv = (const float4*)gcnW;
        Wv[t] = Gv[t];
        Wv[t + 512] = Gv[t + 512];
        sm.x.xr[wid][lane] = xin[(r0 + wid) * DD + lane];
        __syncthreads();
        float s = 0.f;
        #pragma unroll
        for (int k = 0; k < DD; k++) s = fmaf(sm.x.xr[wid][k], sm.x.Ws[k][lane], s);
        xwout[(r0 + wid) * DD + lane] = s;
    }
}

// ---------- gather: cur[n] = dinv[n]*(sum_s dinv[s]*xw[s] + dinv[n]*xw[n]) + b ----------
__global__ __launch_bounds__(512) void k_gather(const int* __restrict__ cnt,
                                                const float* __restrict__ dinvF,
                                                const int* __restrict__ csr,
                                                const float* __restrict__ xw,
                                                const float* __restrict__ bvec,
                                                float* __restrict__ cur) {
    int t = threadIdx.x, lane = t & 63, wid = t >> 6;
    int n = blockIdx.x * 8 + wid;
    int ecn = cnt[n];
    int ec = ecn > CAP ? CAP : ecn;
    const int* lst = csr + n * CAP;
    float sum0 = 0.f, sum1 = 0.f, sum2 = 0.f, sum3 = 0.f;
    int j = 0;
    for (; j + 4 <= ec; j += 4) {
        int s0 = lst[j], s1 = lst[j + 1], s2 = lst[j + 2], s3 = lst[j + 3];
        sum0 = fmaf(dinvF[s0], xw[s0 * DD + lane], sum0);
        sum1 = fmaf(dinvF[s1], xw[s1 * DD + lane], sum1);
        sum2 = fmaf(dinvF[s2], xw[s2 * DD + lane], sum2);
        sum3 = fmaf(dinvF[s3], xw[s3 * DD + lane], sum3);
    }
    for (; j < ec; j++) {
        int s0 = lst[j];
        sum0 = fmaf(dinvF[s0], xw[s0 * DD + lane], sum0);
    }
    float di = dinvF[n];
    cur[n * DD + lane] = di * (((sum0 + sum1) + (sum2 + sum3)) + di * xw[n * DD + lane])
                         + bvec[lane];
}

// ---------- fin: att-pool(cur2) + cls head + kpart reduction + combine ----------
__global__ __launch_bounds__(512) void k_fin(const float* __restrict__ cur2,
    const float* __restrict__ gW2, const float* __restrict__ gb2,
    const float* __restrict__ clsW, const float* __restrict__ clsB,
    const float* __restrict__ hb, const float* __restrict__ kpart,
    const float* __restrict__ kpb0, const float* __restrict__ kpb1,
    const float* __restrict__ beta, const float* __restrict__ h0s,
    float* __restrict__ out) {
    __shared__ AttS sa;
    __shared__ float red2[32][16];
    __shared__ float red[16];
    int g = blockIdx.x, t = threadIdx.x;
    att_pool(sa, cur2 + g * NPG * DD, gW2, gb2[0]);
    // kpart reduction: 2 layers x 64 partial vectors -> red2[32][16]
    {
        int j = t & 15, u = t >> 4;   // u: (layer<<4)|dim-group
        int L = u >> 4, dg = u & 15;
        float s = 0.f;
        #pragma unroll
        for (int dd2 = 0; dd2 < 4; dd2++) {
            int d = dg * 4 + dd2;
            s += kpart[(L * GG * DD + g * DD + d) * 16 + j];
        }
        red2[u][j] = s;
    }
    __syncthreads();
    if (t < 16) {
        float sk = 0.f;
        #pragma unroll
        for (int u2 = 0; u2 < 32; u2++) sk += red2[u2][t];
        float h2 = clsB[t];
        #pragma unroll
        for (int d3 = 0; d3 < DD; d3++) h2 = fmaf(sa.pooled[d3], clsW[d3 * 16 + t], h2);
        float mo = (hb[g * 16 + t] + hb[256 + g * 16 + t] + h2) * (1.f / 3.f);
        float ko = (sk + kpb0[t] + kpb1[t]) * 0.5f;
        red[t] = (mo + ko) * beta[t];
    }
    __syncthreads();
    if (t == 0) {
        float s = 0.f;
        #pragma unroll
        for (int j = 0; j < 16; j++) s += red[j];
        out[g] = s + h0s[0];
    }
}

extern "C" void kernel_launch(void* const* d_in, const int* in_sizes, int n_in,
                              void* d_out, int out_size, void* d_ws, size_t ws_size,
                              hipStream_t stream) {
    const float* x       = (const float*)d_in[0];
    const int*   ei      = (const int*)  d_in[1];
    const float* gcn_W0  = (const float*)d_in[2];
    const float* gcn_b0  = (const float*)d_in[3];
    const float* gcn_W1  = (const float*)d_in[4];
    const float* gcn_b1  = (const float*)d_in[5];
    const float* lp_W0   = (const float*)d_in[6];
    const float* lp_b0   = (const float*)d_in[7];
    const float* lp_W1   = (const float*)d_in[8];
    const float* lp_b1   = (const float*)d_in[9];
    const float* cls_W   = (const float*)d_in[10];
    const float* cls_b   = (const float*)d_in[11];
    const float* kp_W0   = (const float*)d_in[12];
    const float* kp_b0   = (const float*)d_in[13];
    const float* kp_W1   = (const float*)d_in[14];
    const float* kp_b1   = (const float*)d_in[15];
    const float* gate_W0 = (const float*)d_in[16];
    const float* gate_b0 = (const float*)d_in[17];
    const float* gate_W1 = (const float*)d_in[18];
    const float* gate_b1 = (const float*)d_in[19];
    const float* gate_W2 = (const float*)d_in[20];
    const float* gate_b2 = (const float*)d_in[21];
    const float* beta    = (const float*)d_in[22];
    const float* h0s     = (const float*)d_in[23];

    float* ws = (float*)d_ws;
    int* cnt     = (int*)ws;                        // [2048]
    float* dinvF = ws + NNODE;                      // [2048]
    int* csr     = (int*)(ws + 2 * NNODE);          // [2048*64]
    float* A     = (float*)(csr + NNODE * CAP);     // xw [131072]
    float* B     = A + NNODE * DD;                  // cur [131072]
    float* hb    = B + NNODE * DD;                  // [512] (h0: +0, h1: +256)
    float* kp    = hb + 512;                        // kpart [2][1024*16]

    const int NMEGA = GG * DD + GG + NNODE / 8;     // 1296

    // D1: 64 CSR-build blocks FIRST (overlap with round-1 compute) + mega L0
    k_mega<<<64 + NMEGA, 512, 0, stream>>>(
        x, ei, cnt, csr, dinvF, A, hb, kp,
        gcn_W0, gate_W0, gate_b0, lp_W0, lp_b0, kp_W0, 64);

    // D2: gather L0 -> B (cur1)
    k_gather<<<NNODE / 8, 512, 0, stream>>>(cnt, dinvF, csr, A, gcn_b0, B);

    // D3: mega L1
    k_mega<<<NMEGA, 512, 0, stream>>>(
        B, ei, cnt, csr, dinvF, A, hb + 256, kp + GG * DD * 16,
        gcn_W1, gate_W1, gate_b1, lp_W1, lp_b1, kp_W1, 0);

    // D4: gather L1 -> B (cur2)
    k_gather<<<NNODE / 8, 512, 0, stream>>>(cnt, dinvF, csr, A, gcn_b1, B);

    // D5: final pool + combine
    k_fin<<<GG, 512, 0, stream>>>(B, gate_W2, gate_b2, cls_W, cls_b,
                                  hb, kp, kp_b0, kp_b1, beta, h0s, (float*)d_out);
}

// Round 12
// 57.938 us; speedup vs baseline: 4.1609x; 1.0093x over previous
//
#include <hip/hip_runtime.h>
#include <math.h>

#define NNODE 2048
#define NEDGE 32768
#define DD 64
#define GG 16
#define NPG 128   // nodes per graph
#define PP 500    // kde grid points
#define QQ 20     // quantiles
#define CAP 64    // adjacency bucket capacity (max in-degree ~35 here)

__device__ __forceinline__ float fexp2(float x) { return __builtin_amdgcn_exp2f(x); }
__device__ __forceinline__ float frcp(float x)  { return __builtin_amdgcn_rcpf(x); }
__device__ __forceinline__ float frsq(float x)  { return __builtin_amdgcn_rsqf(x); }

struct __align__(8) f2 { float x, y; };

struct KdeS { f2 bc[NPG]; f2 cg[512]; float sred[8]; float wtot[8]; float kfv[QQ]; };
struct AttS { float sc[NPG]; float part[8][DD]; float pooled[DD]; };
struct XwS  { float Ws[DD][DD]; float xr[8][DD]; };
struct CsrS { int lcnt[32]; };
union SmemU { KdeS k; AttS a; XwS x; CsrS c; };

// ---------- attention-pool helper (512 threads), input from global ----------
__device__ __forceinline__ void att_pool(AttS& s, const float* __restrict__ xg,
                                         const float* __restrict__ gW, float gb) {
    int t = threadIdx.x, lane = t & 63, wid = t >> 6;
    int node = t >> 2, seg = t & 3;
    const float* row = xg + node * DD + seg * 16;
    const float* gw = gW + seg * 16;
    float v = 0.f;
    #pragma unroll
    for (int k = 0; k < 16; k++) v = fmaf(row[k], gw[k], v);
    v += __shfl_xor(v, 1);
    v += __shfl_xor(v, 2);
    if (seg == 0) s.sc[node] = v + gb;
    __syncthreads();
    if (wid == 0) {
        float v0 = s.sc[lane], v1 = s.sc[lane + 64];
        float m = fmaxf(v0, v1);
        for (int o = 32; o; o >>= 1) m = fmaxf(m, __shfl_xor(m, o));
        float e0 = __expf(v0 - m), e1 = __expf(v1 - m);
        float ssum = e0 + e1;
        for (int o = 32; o; o >>= 1) ssum += __shfl_xor(ssum, o);
        float inv = frcp(ssum);
        s.sc[lane] = e0 * inv;
        s.sc[lane + 64] = e1 * inv;
    }
    __syncthreads();
    int d2 = t & 63, ch = t >> 6;
    const float* base = xg + ch * 16 * DD + d2;
    const float* av = s.sc + ch * 16;
    float p = 0.f;
    #pragma unroll
    for (int i = 0; i < 16; i++) p = fmaf(av[i], base[i * DD], p);
    s.part[ch][d2] = p;
    __syncthreads();
    if (t < DD) {
        float pd = 0.f;
        #pragma unroll
        for (int c2 = 0; c2 < 8; c2++) pd += s.part[c2][t];
        s.pooled[t] = pd;
    }
    __syncthreads();
}

// ---------- mega kernel ----------
// vb<csrBlocks: CSR build (D1 only, FIRST so it overlaps round-1 compute blocks)
// then u=vb-csrBlocks: u<1024 KDE | u<1040 att-pool+head | u<1296 xw=x@W (unscaled)
__global__ __launch_bounds__(512) void k_mega(
    const float* __restrict__ xin, const int* __restrict__ ei,
    int* __restrict__ cnt, int* __restrict__ csr, float* __restrict__ dinvF,
    float* __restrict__ xwout, float* __restrict__ hbL, float* __restrict__ kpartL,
    const float* __restrict__ gcnW,
    const float* __restrict__ gateW, const float* __restrict__ gateB,
    const float* __restrict__ lpW, const float* __restrict__ lpB,
    const float* __restrict__ kpW, int csrBlocks) {
    __shared__ SmemU sm;
    int vb = blockIdx.x, t = threadIdx.x, lane = t & 63, wid = t >> 6;

    if (vb < csrBlocks) {
        // ================= parallel CSR build: block owns 32 dst nodes =================
        int base = vb * 32;
        if (t < 32) sm.c.lcnt[t] = 0;
        __syncthreads();
        for (int c = 0; c < NEDGE / 512; c++) {
            int e = c * 512 + t;
            int dstn = ei[NEDGE + e];
            unsigned rel = (unsigned)(dstn - base);
            if (rel < 32u) {
                int s = ei[e];
                int pos = atomicAdd(&sm.c.lcnt[rel], 1);
                if (pos < CAP) csr[dstn * CAP + pos] = s;
            }
        }
        __syncthreads();
        if (t < 32) {
            int c = sm.c.lcnt[t];
            cnt[base + t] = c;
            dinvF[base + t] = frsq((float)c + 1.0f);
        }
        return;
    }
    int u = vb - csrBlocks;

    if (u < GG * DD) {
        // ================= KDE: one block per (g,d) =================
        int g = u >> 6, d = u & 63;
        const float* xg = xin + g * NPG * DD + d;
        float a = 0.f;
        if (t < NPG) a = xg[t * DD];
        // one-pass stats: mn, mx, sum, sumsq (waves 0,1)
        if (wid < 2) {
            float mn = a, mx = a, smv = a, sq = a * a;
            for (int o = 32; o; o >>= 1) {
                mn = fminf(mn, __shfl_xor(mn, o));
                mx = fmaxf(mx, __shfl_xor(mx, o));
                smv += __shfl_xor(smv, o);
                sq += __shfl_xor(sq, o);
            }
            if (lane == 0) {
                sm.k.sred[wid * 4 + 0] = mn;
                sm.k.sred[wid * 4 + 1] = mx;
                sm.k.sred[wid * 4 + 2] = smv;
                sm.k.sred[wid * 4 + 3] = sq;
            }
        }
        __syncthreads();
        float mn = fminf(sm.k.sred[0], sm.k.sred[4]) - 1e-6f;
        float mx = fmaxf(sm.k.sred[1], sm.k.sred[5]) + 1e-6f;
        float mean = (sm.k.sred[2] + sm.k.sred[6]) * (1.f / 128.f);
        float ex2 = (sm.k.sred[3] + sm.k.sred[7]) * (1.f / 128.f);
        float var = fmaxf(ex2 - mean * mean, 0.f);
        float sd = sqrtf(var) + (1e-8f / 3.0f);
        float h = 0.4016648901252554f * sd;          // 1.06 * 128^-0.2 * std
        float A = -0.5f * 1.4426950408889634f * frcp(h * h);
        if (t < NPG) { f2 v; v.x = -2.f * A * a; v.y = A * a * a; sm.k.bc[t] = v; }
        __syncthreads();
        float step = (mx - mn) * (1.f / 499.f);
        float gp = fmaf(step, (float)t, mn);
        float gA = A * gp * gp;
        const float4* bc4 = (const float4*)sm.k.bc;
        float ac0 = 0.f, ac1 = 0.f, ac2 = 0.f, ac3 = 0.f;
        #pragma unroll 4
        for (int j4 = 0; j4 < 64; j4 += 2) {
            float4 p = bc4[j4], q = bc4[j4 + 1];
            ac0 += fexp2(gA + fmaf(p.x, gp, p.y));
            ac1 += fexp2(gA + fmaf(p.z, gp, p.w));
            ac2 += fexp2(gA + fmaf(q.x, gp, q.y));
            ac3 += fexp2(gA + fmaf(q.z, gp, q.w));
        }
        float invnh = frcp(128.f * h * 2.5066282746310002f);
        float dens = (t < PP) ? ((ac0 + ac1) + (ac2 + ac3)) * invnh : 0.f;
        float sc2 = dens;
        for (int o = 1; o < 64; o <<= 1) {
            float uu = __shfl_up(sc2, o);
            if (lane >= o) sc2 += uu;
        }
        if (lane == 63) sm.k.wtot[wid] = sc2;
        __syncthreads();
        float offs = 0.f, total = 0.f;
        #pragma unroll
        for (int w = 0; w < 8; w++) {
            float wv = sm.k.wtot[w];
            if (w < wid) offs += wv;
            total += wv;
        }
        float c = (offs + sc2) * frcp(fmaxf(total, 1e-8f));
        f2 cgv; cgv.x = (t < PP) ? c : 4.0f; cgv.y = (t < PP) ? gp : 0.f;
        sm.k.cg[t] = cgv;
        __syncthreads();
        int grp = t >> 4, sub = t & 15;
        if (grp < QQ) {
            float qv = (float)grp * (1.f / 19.f);
            float sw0 = 0.f, sw1 = 0.f, sg0 = 0.f, sg1 = 0.f;
            #pragma unroll
            for (int i = 0; i < 32; i += 2) {
                f2 v0 = sm.k.cg[i * 16 + sub];
                f2 v1 = sm.k.cg[(i + 1) * 16 + sub];
                float e0 = fexp2(fabsf(v0.x - qv) * 144.26950408889634f);
                float e1 = fexp2(fabsf(v1.x - qv) * 144.26950408889634f);
                float w0 = frcp(1.f + e0), w1 = frcp(1.f + e1);
                sw0 += w0; sg0 = fmaf(w0, v0.y, sg0);
                sw1 += w1; sg1 = fmaf(w1, v1.y, sg1);
            }
            float sw = sw0 + sw1, sg = sg0 + sg1;
            #pragma unroll
            for (int o = 1; o < 16; o <<= 1) {
                sw += __shfl_xor(sw, o);
                sg += __shfl_xor(sg, o);
            }
            if (sub == 0) sm.k.kfv[grp] = sg * frcp(sw + 1e-8f);
        }
        __syncthreads();
        if (t < 16) {
            float v = 0.f;
            #pragma unroll
            for (int q = 0; q < QQ; q++) v = fmaf(sm.k.kfv[q], kpW[(d * QQ + q) * 16 + t], v);
            kpartL[u * 16 + t] = v;
        }
    } else if (u < GG * DD + GG) {
        // ================= attention-pool + linear head =================
        int g = u - GG * DD;
        att_pool(sm.a, xin + g * NPG * DD, gateW, gateB[0]);
        if (t < 16) {
            float o = lpB[t];
            #pragma unroll
            for (int d2 = 0; d2 < DD; d2++) o = fmaf(sm.a.pooled[d2], lpW[d2 * 16 + t], o);
            hbL[g * 16 + t] = o;
        }
    } else {
        // ================= xw = x @ W (unscaled): 8 rows per block =================
        int rb = u - (GG * DD + GG);
        int r0 = rb * 8;
        float4* Wv = (float4*)&sm.x.Ws[0][0];
        const float4* Gv = (const float4*)gcnW;
        Wv[t] = Gv[t];
        Wv[t + 512] = Gv[t + 512];
        sm.x.xr[wid][lane] = xin[(r0 + wid) * DD + lane];
        __syncthreads();
        float s = 0.f;
        #pragma unroll
        for (int k = 0; k < DD; k++) s = fmaf(sm.x.xr[wid][k], sm.x.Ws[k][lane], s);
        xwout[(r0 + wid) * DD + lane] = s;
    }
}

// ---------- gather: 2 waves per node, 4 nodes per block (512 blocks) ----------
// cur[n] = dinv[n]*(sum_s dinv[s]*xw[s] + dinv[n]*xw[n]) + b
__global__ __launch_bounds__(512) void k_gather(const int* __restrict__ cnt,
                                                const float* __restrict__ dinvF,
                                                const int* __restrict__ csr,
                                                const float* __restrict__ xw,
                                                const float* __restrict__ bvec,
                                                float* __restrict__ cur) {
    __shared__ float psum[8][DD];
    int t = threadIdx.x, lane = t & 63, w = t >> 6;
    int n = blockIdx.x * 4 + (w >> 1);   // node for this wave
    int h = w & 1;                        // which half of the edge list
    int ecn = cnt[n];
    int ec = ecn > CAP ? CAP : ecn;
    const int* lst = csr + n * CAP;
    int lo = (ec * h) >> 1, hi = (ec * (h + 1)) >> 1;
    float s0 = 0.f, s1 = 0.f;
    int j = lo;
    for (; j + 2 <= hi; j += 2) {
        int a0 = lst[j], a1 = lst[j + 1];
        s0 = fmaf(dinvF[a0], xw[a0 * DD + lane], s0);
        s1 = fmaf(dinvF[a1], xw[a1 * DD + lane], s1);
    }
    if (j < hi) {
        int a0 = lst[j];
        s0 = fmaf(dinvF[a0], xw[a0 * DD + lane], s0);
    }
    psum[w][lane] = s0 + s1;
    __syncthreads();
    if (h == 0) {
        float tot = psum[w][lane] + psum[w + 1][lane];
        float di = dinvF[n];
        cur[n * DD + lane] = di * (tot + di * xw[n * DD + lane]) + bvec[lane];
    }
}

// ---------- fin: att-pool(cur2) + cls head + kpart reduction + combine ----------
__global__ __launch_bounds__(512) void k_fin(const float* __restrict__ cur2,
    const float* __restrict__ gW2, const float* __restrict__ gb2,
    const float* __restrict__ clsW, const float* __restrict__ clsB,
    const float* __restrict__ hb, const float* __restrict__ kpart,
    const float* __restrict__ kpb0, const float* __restrict__ kpb1,
    const float* __restrict__ beta, const float* __restrict__ h0s,
    float* __restrict__ out) {
    __shared__ AttS sa;
    __shared__ float red2[32][16];
    __shared__ float red[16];
    int g = blockIdx.x, t = threadIdx.x;
    att_pool(sa, cur2 + g * NPG * DD, gW2, gb2[0]);
    // kpart reduction: 2 layers x 64 partial vectors -> red2[32][16]
    {
        int j = t & 15, u = t >> 4;   // u: (layer<<4)|dim-group
        int L = u >> 4, dg = u & 15;
        float s = 0.f;
        #pragma unroll
        for (int dd2 = 0; dd2 < 4; dd2++) {
            int d = dg * 4 + dd2;
            s += kpart[(L * GG * DD + g * DD + d) * 16 + j];
        }
        red2[u][j] = s;
    }
    __syncthreads();
    if (t < 16) {
        float sk = 0.f;
        #pragma unroll
        for (int u2 = 0; u2 < 32; u2++) sk += red2[u2][t];
        float h2 = clsB[t];
        #pragma unroll
        for (int d3 = 0; d3 < DD; d3++) h2 = fmaf(sa.pooled[d3], clsW[d3 * 16 + t], h2);
        float mo = (hb[g * 16 + t] + hb[256 + g * 16 + t] + h2) * (1.f / 3.f);
        float ko = (sk + kpb0[t] + kpb1[t]) * 0.5f;
        red[t] = (mo + ko) * beta[t];
    }
    __syncthreads();
    if (t == 0) {
        float s = 0.f;
        #pragma unroll
        for (int j = 0; j < 16; j++) s += red[j];
        out[g] = s + h0s[0];
    }
}

extern "C" void kernel_launch(void* const* d_in, const int* in_sizes, int n_in,
                              void* d_out, int out_size, void* d_ws, size_t ws_size,
                              hipStream_t stream) {
    const float* x       = (const float*)d_in[0];
    const int*   ei      = (const int*)  d_in[1];
    const float* gcn_W0  = (const float*)d_in[2];
    const float* gcn_b0  = (const float*)d_in[3];
    const float* gcn_W1  = (const float*)d_in[4];
    const float* gcn_b1  = (const float*)d_in[5];
    const float* lp_W0   = (const float*)d_in[6];
    const float* lp_b0   = (const float*)d_in[7];
    const float* lp_W1   = (const float*)d_in[8];
    const float* lp_b1   = (const float*)d_in[9];
    const float* cls_W   = (const float*)d_in[10];
    const float* cls_b   = (const float*)d_in[11];
    const float* kp_W0   = (const float*)d_in[12];
    const float* kp_b0   = (const float*)d_in[13];
    const float* kp_W1   = (const float*)d_in[14];
    const float* kp_b1   = (const float*)d_in[15];
    const float* gate_W0 = (const float*)d_in[16];
    const float* gate_b0 = (const float*)d_in[17];
    const float* gate_W1 = (const float*)d_in[18];
    const float* gate_b1 = (const float*)d_in[19];
    const float* gate_W2 = (const float*)d_in[20];
    const float* gate_b2 = (const float*)d_in[21];
    const float* beta    = (const float*)d_in[22];
    const float* h0s     = (const float*)d_in[23];

    float* ws = (float*)d_ws;
    int* cnt     = (int*)ws;                        // [2048]
    float* dinvF = ws + NNODE;                      // [2048]
    int* csr     = (int*)(ws + 2 * NNODE);          // [2048*64]
    float* A     = (float*)(csr + NNODE * CAP);     // xw [131072]
    float* B     = A + NNODE * DD;                  // cur [131072]
    float* hb    = B + NNODE * DD;                  // [512] (h0: +0, h1: +256)
    float* kp    = hb + 512;                        // kpart [2][1024*16]

    const int NMEGA = GG * DD + GG + NNODE / 8;     // 1296

    // D1: 64 CSR-build blocks FIRST (overlap with round-1 compute) + mega L0
    k_mega<<<64 + NMEGA, 512, 0, stream>>>(
        x, ei, cnt, csr, dinvF, A, hb, kp,
        gcn_W0, gate_W0, gate_b0, lp_W0, lp_b0, kp_W0, 64);

    // D2: gather L0 -> B (cur1)
    k_gather<<<NNODE / 4, 512, 0, stream>>>(cnt, dinvF, csr, A, gcn_b0, B);

    // D3: mega L1
    k_mega<<<NMEGA, 512, 0, stream>>>(
        B, ei, cnt, csr, dinvF, A, hb + 256, kp + GG * DD * 16,
        gcn_W1, gate_W1, gate_b1, lp_W1, lp_b1, kp_W1, 0);

    // D4: gather L1 -> B (cur2)
    k_gather<<<NNODE / 4, 512, 0, stream>>>(cnt, dinvF, csr, A, gcn_b1, B);

    // D5: final pool + combine
    k_fin<<<GG, 512, 0, stream>>>(B, gate_W2, gate_b2, cls_W, cls_b,
                                  hb, kp, kp_b0, kp_b1, beta, h0s, (float*)d_out);
}